// Round 14
// baseline (588.353 us; speedup 1.0000x reference)
//
#include <hip/hip_runtime.h>
#include <math.h>

namespace {
constexpr int NDFT   = 1024;
constexpr int NHOP   = 256;
constexpr int NFILT  = 513;
constexpr int LSRC   = 262144;
constexpr int NFRAME = 1024;
constexpr int PAD_L  = 384;
constexpr long PER_B = (long)NFILT * NFRAME * 2;

// ---- folded tier (K=512) ----
constexpr int KT2 = 16;               // K-tiles of 32 slots
constexpr int CHUNK_US = 8192;        // ushorts per (nt,kt) chunk = 16 KB
constexpr size_t WSB2_BYTES = (size_t)8 * KT2 * CHUNK_US * 2;   // 2 MiB
constexpr size_t PLANE_ELEMS_PER_SIG = 1024 * 512;              // 0.5M elems = 1 MiB

// ---- mid tier (r3 kernel, K=1024) ----
constexpr int KT1 = 32;
constexpr size_t WS_B_BYTES = (size_t)8 * KT1 * CHUNK_US * 2;   // 4 MiB
}

using short8 = __attribute__((ext_vector_type(8))) short;
using f32x4  = __attribute__((ext_vector_type(4))) float;

__device__ __forceinline__ unsigned int f2key(float f) {
    unsigned int u = __float_as_uint(f);
    return (u & 0x80000000u) ? ~u : (u | 0x80000000u);
}
__device__ __forceinline__ float key2f(unsigned int k) {
    return (k & 0x80000000u) ? __uint_as_float(k ^ 0x80000000u) : __uint_as_float(~k);
}
__device__ __forceinline__ unsigned short bf16rn(float v) {
    unsigned int u = __float_as_uint(v);
    return (unsigned short)((u + 0x7fffu + ((u >> 16) & 1u)) >> 16);
}

__global__ void zero_ws(unsigned int* __restrict__ w) {
    if (threadIdx.x < 32) w[threadIdx.x] = 0u;
}

// ---------------------------------------------------------------------------
// Fold prepass: for each frame f, slot s in [0,512):
//   s==0 : sum = diff = x[base+512]            (unpaired t=512 tap)
//   s>=1 : sum = x[base+s] + x[base+1024-s], diff = x[base+s] - x[base+1024-s]
// split each into hi/lo bf16 planes [frame][512]. One wave per frame.
// ---------------------------------------------------------------------------
__global__ __launch_bounds__(256) void fold_split(
    const float* __restrict__ x,
    unsigned short* __restrict__ sH, unsigned short* __restrict__ sL,
    unsigned short* __restrict__ dH, unsigned short* __restrict__ dL,
    int sig0)
{
    const int floc = blockIdx.x * 4 + (threadIdx.x >> 6);  // within-pass frame
    const int grp  = threadIdx.x & 63;                     // 8 slots each
    const int sig  = sig0 + (floc >> 10);
    const int fl   = floc & 1023;
    const long sbase = (long)sig * LSRC;
    const int st   = fl * NHOP - PAD_L;                    // mod 8 == 0
    const int s0   = grp * 8;

    const float xmid = x[sbase + st + 512];                // always in bounds

    float fw[8], bw[8];                                    // bw[j] = x2 for slot s0+j
    if (fl >= 2 && fl <= 1021) {
        const float4 a0 = *reinterpret_cast<const float4*>(x + sbase + st + s0);
        const float4 a1 = *reinterpret_cast<const float4*>(x + sbase + st + s0 + 4);
        fw[0]=a0.x; fw[1]=a0.y; fw[2]=a0.z; fw[3]=a0.w;
        fw[4]=a1.x; fw[5]=a1.y; fw[6]=a1.z; fw[7]=a1.w;
        const long q0 = sbase + st + 1017 - s0;            // q0-1 is 32B aligned
        const float4 b0 = *reinterpret_cast<const float4*>(x + q0 - 1);
        const float4 b1 = *reinterpret_cast<const float4*>(x + q0 + 3);
        const float  b2 = x[q0 + 7];
        const float va[8] = {b0.y, b0.z, b0.w, b1.x, b1.y, b1.z, b1.w, b2}; // va[i]=x[q0+i]
        #pragma unroll
        for (int j = 0; j < 8; ++j) bw[j] = va[7 - j];
    } else {
        #pragma unroll
        for (int j = 0; j < 8; ++j) {
            const int s = s0 + j;
            const int p1 = st + s;
            const int p2 = st + 1024 - s;
            fw[j] = ((unsigned)p1 < (unsigned)LSRC) ? x[sbase + p1] : 0.0f;
            bw[j] = ((unsigned)p2 < (unsigned)LSRC) ? x[sbase + p2] : 0.0f;
        }
    }

    union { unsigned short u[8]; uint4 v; } shv, slv, dhv, dlv;
    #pragma unroll
    for (int j = 0; j < 8; ++j) {
        float x1 = fw[j], x2 = bw[j];
        if (j == 0 && s0 == 0) { x1 = xmid; x2 = 0.0f; }
        const float sm = x1 + x2;
        const float df = x1 - x2;
        const unsigned short h1 = bf16rn(sm);
        shv.u[j] = h1;
        slv.u[j] = bf16rn(sm - __uint_as_float((unsigned int)h1 << 16));
        const unsigned short h2 = bf16rn(df);
        dhv.u[j] = h2;
        dlv.u[j] = bf16rn(df - __uint_as_float((unsigned int)h2 << 16));
    }
    const size_t wo = (size_t)floc * 512 + s0;
    *reinterpret_cast<uint4*>(sH + wo) = shv.v;
    *reinterpret_cast<uint4*>(sL + wo) = slv.v;
    *reinterpret_cast<uint4*>(dH + wo) = dhv.v;
    *reinterpret_cast<uint4*>(dL + wo) = dlv.v;
}

// ---------------------------------------------------------------------------
// Folded-B build: chunk per (nt,kt): rows n in [0,128): n<64 -> kr (cos) bin
// nt*64+n; n>=64 -> ki (sin) bin nt*64+n-64. Slot s = kt*32+c*8+i maps to
// DFT row t = (s==0) ? 512 : s. Hi/lo + XOR-swizzled 16 KB LDS-image chunks.
// ---------------------------------------------------------------------------
__global__ __launch_bounds__(256) void build_B2(const float* __restrict__ kr,
                                                const float* __restrict__ ki,
                                                unsigned short* __restrict__ wsB)
{
    const int nt = blockIdx.x >> 4;
    const int kt = blockIdx.x & 15;
    unsigned short* chunk = wsB + (size_t)blockIdx.x * CHUNK_US;
    const int col = threadIdx.x >> 1;        // 0..127
    const int h   = threadIdx.x & 1;
    const int bin = nt * 64 + (col & 63);
    const float* src = (col < 64) ? kr : ki;
    #pragma unroll
    for (int j = 0; j < 4; ++j) {
        const int sl = h * 4 + j;
        const int c  = sl & 3;
        union { unsigned short u[8]; uint4 v; } pk;
        #pragma unroll
        for (int i = 0; i < 8; ++i) {
            const int s = kt * 32 + c * 8 + i;
            const int t = (s == 0) ? 512 : s;
            const float v = src[t * NFILT + bin];
            const unsigned short hi = bf16rn(v);
            pk.u[i] = h ? bf16rn(v - __uint_as_float((unsigned int)hi << 16)) : hi;
        }
        *reinterpret_cast<uint4*>(&chunk[col * 64 + ((sl ^ (col & 7)) << 3)]) = pk.v;
    }
}

// ---------------------------------------------------------------------------
// Folded GEMM, LDS-staged (r13 base, 330us @ MfmaUtil 27%). r13 residency
// diagnosis: 84 VGPR + 64 AGPR = 148 unified > 128 -> only 8 waves/CU (2
// blocks). This version keeps the SAME 128x128 tile + 48 KB LDS but uses
// 8 WAVES (512 thr), wave-tile 64x32 -> acc[4][2] = 32 AGPR, ~100 unified
// regs <= 128 -> 16 waves/CU: 2x the latency-hiding pool for the same
// per-CU MFMA work and TA traffic. Waves: wn = w>>2 (0=cos/sum, 1=sin/
// diff); within wn, mh = (w>>1)&1 picks row-half, nhl = w&1 picks col-half.
// ---------------------------------------------------------------------------
__global__ __launch_bounds__(512, 2) void spec_gemm2(
    const unsigned short* __restrict__ sH, const unsigned short* __restrict__ sL,
    const unsigned short* __restrict__ dH, const unsigned short* __restrict__ dL,
    const unsigned short* __restrict__ wsB,
    float* __restrict__ out, unsigned int* __restrict__ wmax,
    int sig0, int nsig)
{
    __shared__ unsigned short smem[24576];  // 48 KB: wn*{A 8192us | B 4096us}

    const int tid  = threadIdx.x;
    const int lane = tid & 63, w = tid >> 6;    // 8 waves
    const int wn  = w >> 2;                     // 0: cos/sum, 1: sin/diff
    const int wm_ = w & 3;                      // within-wn wave id
    const int mh  = wm_ >> 1, nhl = wm_ & 1;    // row-half, col-half
    const int l15 = lane & 15, l16 = lane >> 4;

    const int phys = blockIdx.x;                // 0 .. nsig*64-1
    const int xcd  = phys & 7, slot = phys >> 3;
    const int nt   = slot & 7;
    const int mt   = xcd * nsig + (slot >> 3);  // within-pass mt
    const int sig  = sig0 + (mt >> 3);
    const int f0   = (mt & 7) * 128;            // within-signal frame base
    const unsigned short* bchunks = wsB + (size_t)nt * KT2 * CHUNK_US;

    const unsigned short* __restrict__ pH = wn ? dH : sH;
    const unsigned short* __restrict__ pL = wn ? dL : sL;

    // A gather lane constants: lane = (rl row-in-8, jj 16B-slot); LDS pos jj
    // of row r holds global slot q = jj ^ (r&7); q<4 -> hi octet q, else lo.
    const int rl = lane >> 3, jj = lane & 7;
    const int q  = jj ^ rl;
    const unsigned short* apl = (q < 4) ? pH : pL;
    const unsigned short* agsrc[4];
    #pragma unroll
    for (int i = 0; i < 4; ++i)
        agsrc[i] = apl + (size_t)(mt * 128 + wm_ * 32 + i * 8 + rl) * 512 + (q & 3) * 8;

    unsigned short* Areg  = smem + wn * 12288;
    unsigned short* Breg  = Areg + 8192;
    unsigned short* aldst = Areg + wm_ * 2048;  // wave stages rows wm_*32..+32
    unsigned short* bldst = Breg + wm_ * 1024;  // wave stages 2 KB of B

    f32x4 acc[4][2];
    #pragma unroll
    for (int i = 0; i < 4; ++i)
        #pragma unroll
        for (int j = 0; j < 2; ++j)
            #pragma unroll
            for (int r = 0; r < 4; ++r) acc[i][j][r] = 0.0f;

    #define STAGE(ktv)                                                         \
        {                                                                      \
            _Pragma("unroll")                                                  \
            for (int i = 0; i < 4; ++i)                                        \
                __builtin_amdgcn_global_load_lds(                              \
                    (const __attribute__((address_space(1))) unsigned int*)(agsrc[i] + (ktv) * 32), \
                    (__attribute__((address_space(3))) unsigned int*)(aldst + i * 512), \
                    16, 0, 0);                                                 \
            const unsigned short* gBs = bchunks + (size_t)(ktv) * CHUNK_US + wn * 4096 + wm_ * 1024; \
            _Pragma("unroll")                                                  \
            for (int i = 0; i < 2; ++i)                                        \
                __builtin_amdgcn_global_load_lds(                              \
                    (const __attribute__((address_space(1))) unsigned int*)(gBs + i * 512 + lane * 8), \
                    (__attribute__((address_space(3))) unsigned int*)(bldst + i * 512), \
                    16, 0, 0);                                                 \
        }

    #define COMPUTE()                                                         \
        {                                                                      \
            short8 ah[4], al[4], bh[2], bl[2];                                 \
            _Pragma("unroll")                                                  \
            for (int mf = 0; mf < 4; ++mf) {                                   \
                const int row = mh * 64 + mf * 16 + l15;                       \
                const unsigned short* ab = Areg + row * 64;                    \
                ah[mf] = *reinterpret_cast<const short8*>(ab + ((l16 ^ (row & 7)) << 3));        \
                al[mf] = *reinterpret_cast<const short8*>(ab + (((4 + l16) ^ (row & 7)) << 3));  \
            }                                                                  \
            _Pragma("unroll")                                                  \
            for (int nf = 0; nf < 2; ++nf) {                                   \
                const int coll = nhl * 32 + nf * 16 + l15;                     \
                const unsigned short* bb = Breg + coll * 64;                   \
                bh[nf] = *reinterpret_cast<const short8*>(bb + ((l16 ^ (coll & 7)) << 3));       \
                bl[nf] = *reinterpret_cast<const short8*>(bb + (((4 + l16) ^ (coll & 7)) << 3)); \
            }                                                                  \
            __builtin_amdgcn_s_setprio(1);                                     \
            _Pragma("unroll")                                                  \
            for (int nf = 0; nf < 2; ++nf)                                     \
                _Pragma("unroll")                                              \
                for (int mf = 0; mf < 4; ++mf) {                               \
                    acc[mf][nf] = __builtin_amdgcn_mfma_f32_16x16x32_bf16(ah[mf], bh[nf], acc[mf][nf], 0, 0, 0); \
                    acc[mf][nf] = __builtin_amdgcn_mfma_f32_16x16x32_bf16(al[mf], bh[nf], acc[mf][nf], 0, 0, 0); \
                    acc[mf][nf] = __builtin_amdgcn_mfma_f32_16x16x32_bf16(ah[mf], bl[nf], acc[mf][nf], 0, 0, 0); \
                }                                                              \
            __builtin_amdgcn_s_setprio(0);                                     \
        }

    #pragma unroll 1
    for (int kt = 0; kt < KT2; ++kt) {
        STAGE(kt)
        __syncthreads();
        COMPUTE()
        __syncthreads();
    }
    #undef STAGE
    #undef COMPUTE

    // ---- epilogue: wn=0 writes re^2 (bf16) into smem (aliases buffers);
    //      wn=1 combines re^2+im^2, dB, store + per-batch max ----
    if (wn == 0) {
        #pragma unroll
        for (int mf = 0; mf < 4; ++mf)
            #pragma unroll
            for (int nf = 0; nf < 2; ++nf) {
                const int binl = nhl * 32 + nf * 16 + l15;
                #pragma unroll
                for (int r = 0; r < 4; ++r) {
                    const int row = mh * 64 + mf * 16 + l16 * 4 + r;
                    const float v = acc[mf][nf][r];
                    smem[row * 68 + binl] = bf16rn(v * v);
                }
            }
    }
    __syncthreads();
    if (wn == 1) {
        const int batch = sig >> 1, ch = sig & 1;
        float lmax = -3.0e38f;
        #pragma unroll
        for (int mf = 0; mf < 4; ++mf)
            #pragma unroll
            for (int nf = 0; nf < 2; ++nf) {
                const int binl = nhl * 32 + nf * 16 + l15;
                const int bin  = nt * 64 + binl;
                #pragma unroll
                for (int r = 0; r < 4; ++r) {
                    const int row = mh * 64 + mf * 16 + l16 * 4 + r;
                    const float v = acc[mf][nf][r];
                    const float re2 = __uint_as_float((unsigned int)smem[row * 68 + binl] << 16);
                    const float p = re2 + v * v;
                    const float d = 10.0f * log10f(fmaxf(p, 1e-10f));
                    const int frame = f0 + row;
                    out[((long)(batch * NFILT + bin) * NFRAME + frame) * 2 + ch] = d;
                    lmax = fmaxf(lmax, d);
                }
            }
        #pragma unroll
        for (int off = 32; off > 0; off >>= 1) lmax = fmaxf(lmax, __shfl_xor(lmax, off));
        if (lane == 0) atomicMax(&wmax[batch], f2key(lmax));
    }
}

// ---------------------------------------------------------------------------
// Mid-tier GEMM (round-3 proven kernel, K=1024, LDS-staged A) for small ws.
// ---------------------------------------------------------------------------
__global__ __launch_bounds__(256) void build_B(const float* __restrict__ kr,
                                               const float* __restrict__ ki,
                                               unsigned short* __restrict__ wsB)
{
    const int nt = blockIdx.x >> 5;
    const int kt = blockIdx.x & 31;
    unsigned short* chunk = wsB + (size_t)blockIdx.x * CHUNK_US;
    const int col = threadIdx.x >> 1;
    const int h   = threadIdx.x & 1;
    const int bin = nt * 64 + (col >> 1);
    const float* src = (col & 1) ? ki : kr;
    #pragma unroll
    for (int j = 0; j < 4; ++j) {
        const int sl = h * 4 + j;
        const int c  = sl & 3;
        union { unsigned short u[8]; uint4 v; } pk;
        #pragma unroll
        for (int i = 0; i < 8; ++i) {
            const int t = kt * 32 + c * 8 + i;
            const float v = src[t * NFILT + bin];
            const unsigned short hi = bf16rn(v);
            pk.u[i] = h ? bf16rn(v - __uint_as_float((unsigned int)hi << 16)) : hi;
        }
        *reinterpret_cast<uint4*>(&chunk[col * 64 + ((sl ^ (col & 7)) << 3)]) = pk.v;
    }
}

__global__ __launch_bounds__(256, 2) void spec_gemm_mid(
    const float* __restrict__ x, const unsigned short* __restrict__ wsB,
    float* __restrict__ out, unsigned int* __restrict__ wmax)
{
    __shared__ unsigned short Ad[2][128][64];
    __shared__ unsigned short Bd[2][128][64];

    const int tid  = threadIdx.x;
    const int lane = tid & 63, w = tid >> 6;
    const int wm = w >> 1, wn = w & 1;
    const int l15 = lane & 15, l16 = lane >> 4;
    const int mt = blockIdx.x, nt = blockIdx.y;
    const int sig = mt >> 3, f0 = (mt & 7) * 128;
    const long sb = (long)sig * LSRC;

    const int arow = tid >> 1, ac2 = tid & 1;
    const int abase_p = (f0 + arow) * NHOP - PAD_L + ac2 * 16;
    const unsigned short* bchunks = wsB + (size_t)nt * KT1 * CHUNK_US;

    f32x4 acc[4][4];
    #pragma unroll
    for (int i = 0; i < 4; ++i)
        #pragma unroll
        for (int j = 0; j < 4; ++j)
            #pragma unroll
            for (int r = 0; r < 4; ++r) acc[i][j][r] = 0.0f;

    float va[16];

    #define LOAD_A(ktv)                                                        \
        {                                                                      \
            const int p0 = abase_p + (ktv) * 32;                               \
            if (p0 >= 0 && p0 + 16 <= LSRC) {                                  \
                *reinterpret_cast<float4*>(&va[0])  = *reinterpret_cast<const float4*>(x + sb + p0);      \
                *reinterpret_cast<float4*>(&va[4])  = *reinterpret_cast<const float4*>(x + sb + p0 + 4);  \
                *reinterpret_cast<float4*>(&va[8])  = *reinterpret_cast<const float4*>(x + sb + p0 + 8);  \
                *reinterpret_cast<float4*>(&va[12]) = *reinterpret_cast<const float4*>(x + sb + p0 + 12); \
            } else {                                                           \
                _Pragma("unroll")                                              \
                for (int i = 0; i < 16; ++i) {                                 \
                    const int p = p0 + i;                                      \
                    va[i] = (p >= 0 && p < LSRC) ? x[sb + p] : 0.0f;           \
                }                                                              \
            }                                                                  \
        }

    #define LOAD_B(ktv, nb)                                                    \
        {                                                                      \
            const char* g = (const char*)(bchunks + (size_t)(ktv) * CHUNK_US); \
            char* l = (char*)&Bd[nb][0][0];                                    \
            _Pragma("unroll")                                                  \
            for (int i = 0; i < 4; ++i) {                                      \
                const int off = i * 4096 + w * 1024;                           \
                __builtin_amdgcn_global_load_lds(                              \
                    (const __attribute__((address_space(1))) unsigned int*)(g + off + lane * 16), \
                    (__attribute__((address_space(3))) unsigned int*)(l + off), \
                    16, 0, 0);                                                 \
            }                                                                  \
        }

    #define WRITE_A(nb)                                                       \
        {                                                                      \
            unsigned short* ab = &Ad[nb][arow][0];                             \
            _Pragma("unroll")                                                  \
            for (int j = 0; j < 2; ++j) {                                      \
                union { unsigned short u[8]; uint4 v; } hv, lv;                \
                _Pragma("unroll")                                              \
                for (int i = 0; i < 8; ++i) {                                  \
                    const float vv = va[j * 8 + i];                            \
                    const unsigned short hi = bf16rn(vv);                      \
                    hv.u[i] = hi;                                              \
                    lv.u[i] = bf16rn(vv - __uint_as_float((unsigned int)hi << 16)); \
                }                                                              \
                const int c = ac2 * 2 + j;                                     \
                *reinterpret_cast<uint4*>(ab + (((c) ^ (arow & 7)) << 3))     = hv.v; \
                *reinterpret_cast<uint4*>(ab + (((4 + c) ^ (arow & 7)) << 3)) = lv.v; \
            }                                                                  \
        }

    LOAD_A(0)
    LOAD_B(0, 0)
    WRITE_A(0)
    __syncthreads();

    #pragma unroll 1
    for (int kt = 0; kt < KT1; ++kt) {
        const int cur = kt & 1, nxt = cur ^ 1;
        const bool pf = (kt + 1 < KT1);
        if (pf) {
            LOAD_A(kt + 1)
            LOAD_B(kt + 1, nxt)
        }
        short8 ah[4], al[4];
        #pragma unroll
        for (int mf = 0; mf < 4; ++mf) {
            const int row = wm * 64 + mf * 16 + l15;
            const unsigned short* ab = &Ad[cur][row][0];
            ah[mf] = *reinterpret_cast<const short8*>(ab + ((l16 ^ (row & 7)) << 3));
            al[mf] = *reinterpret_cast<const short8*>(ab + (((4 + l16) ^ (row & 7)) << 3));
        }
        __builtin_amdgcn_s_setprio(1);
        #pragma unroll
        for (int nf = 0; nf < 4; ++nf) {
            const int col = wn * 64 + nf * 16 + l15;
            const unsigned short* bb = &Bd[cur][col][0];
            const short8 bh = *reinterpret_cast<const short8*>(bb + ((l16 ^ (col & 7)) << 3));
            const short8 bl = *reinterpret_cast<const short8*>(bb + (((4 + l16) ^ (col & 7)) << 3));
            #pragma unroll
            for (int mf = 0; mf < 4; ++mf) {
                acc[mf][nf] = __builtin_amdgcn_mfma_f32_16x16x32_bf16(ah[mf], bh, acc[mf][nf], 0, 0, 0);
                acc[mf][nf] = __builtin_amdgcn_mfma_f32_16x16x32_bf16(al[mf], bh, acc[mf][nf], 0, 0, 0);
                acc[mf][nf] = __builtin_amdgcn_mfma_f32_16x16x32_bf16(ah[mf], bl, acc[mf][nf], 0, 0, 0);
            }
        }
        __builtin_amdgcn_s_setprio(0);
        if (pf) WRITE_A(nxt)
        __syncthreads();
    }
    #undef LOAD_A
    #undef LOAD_B
    #undef WRITE_A

    const int batch = sig >> 1, ch = sig & 1;
    float lmax = -3.0e38f;
    #pragma unroll
    for (int mf = 0; mf < 4; ++mf)
        #pragma unroll
        for (int nf = 0; nf < 4; ++nf) {
            const int col = nt * 128 + wn * 64 + nf * 16 + l15;
            const int bin = col >> 1;
            #pragma unroll
            for (int r = 0; r < 4; ++r) {
                const float v  = acc[mf][nf][r];
                const float sq = v * v;
                const float p  = sq + __shfl_xor(sq, 1);
                if (!(lane & 1)) {
                    const int frame = f0 + wm * 64 + mf * 16 + l16 * 4 + r;
                    const float d = 10.0f * log10f(fmaxf(p, 1e-10f));
                    out[((long)(batch * NFILT + bin) * NFRAME + frame) * 2 + ch] = d;
                    lmax = fmaxf(lmax, d);
                }
            }
        }
    #pragma unroll
    for (int off = 32; off > 0; off >>= 1) lmax = fmaxf(lmax, __shfl_xor(lmax, off));
    if (lane == 0) atomicMax(&wmax[batch], f2key(lmax));
}

// ---------------------------------------------------------------------------
// Nyquist bin (512): block = 1 signal x 64 frames, x + coeffs staged in LDS.
// ---------------------------------------------------------------------------
__global__ __launch_bounds__(256, 2) void spec_nyq(
    const float* __restrict__ x, const float* __restrict__ kr,
    const float* __restrict__ ki, float* __restrict__ out,
    unsigned int* __restrict__ wmax)
{
    __shared__ float xs[17152];
    __shared__ float kc[1024], ks[1024];
    const int sig = blockIdx.x >> 4, ft = blockIdx.x & 15;
    const int f0 = ft * 64;
    const long sb = (long)sig * LSRC;
    const int start = f0 * NHOP - PAD_L;
    for (int i = threadIdx.x; i < 17152; i += 256) {
        const int p = start + i;
        xs[i] = (p >= 0 && p < LSRC) ? x[sb + p] : 0.0f;
    }
    for (int t = threadIdx.x; t < 1024; t += 256) {
        kc[t] = kr[t * NFILT + 512];
        ks[t] = ki[t * NFILT + 512];
    }
    __syncthreads();
    const int fr = threadIdx.x >> 2, q = threadIdx.x & 3;
    const int rot = ((fr + q) & 7) * 4;
    float re = 0.0f, im = 0.0f;
    #pragma unroll 4
    for (int j = 0; j < 256; j += 4) {
        const int je = (j + rot) & 255;
        const float4 a = *reinterpret_cast<const float4*>(&xs[fr * 256 + q * 256 + je]);
        const float4 c = *reinterpret_cast<const float4*>(&kc[q * 256 + je]);
        const float4 s = *reinterpret_cast<const float4*>(&ks[q * 256 + je]);
        re = fmaf(a.x, c.x, re); re = fmaf(a.y, c.y, re);
        re = fmaf(a.z, c.z, re); re = fmaf(a.w, c.w, re);
        im = fmaf(a.x, s.x, im); im = fmaf(a.y, s.y, im);
        im = fmaf(a.z, s.z, im); im = fmaf(a.w, s.w, im);
    }
    re += __shfl_xor(re, 1); re += __shfl_xor(re, 2);
    im += __shfl_xor(im, 1); im += __shfl_xor(im, 2);
    const int batch = sig >> 1, ch = sig & 1;
    float lmax = -3.0e38f;
    if (q == 0) {
        const float p = re * re + im * im;
        const float d = 10.0f * log10f(fmaxf(p, 1e-10f));
        out[((long)(batch * NFILT + 512) * NFRAME + (f0 + fr)) * 2 + ch] = d;
        lmax = d;
    }
    #pragma unroll
    for (int off = 32; off > 0; off >>= 1) lmax = fmaxf(lmax, __shfl_xor(lmax, off));
    if ((threadIdx.x & 63) == 0) atomicMax(&wmax[batch], f2key(lmax));
}

__global__ __launch_bounds__(256) void finalize(
    float* __restrict__ out, const unsigned int* __restrict__ wmax, long n4)
{
    const long stride = (long)gridDim.x * 256;
    for (long i4 = blockIdx.x * 256L + threadIdx.x; i4 < n4; i4 += stride) {
        const long i = i4 * 4;
        const int b  = (int)(i / PER_B);
        const float m = key2f(wmax[b]);
        float4 v = reinterpret_cast<float4*>(out)[i4];
        v.x = fmaxf(v.x - m, -80.0f);
        v.y = fmaxf(v.y - m, -80.0f);
        v.z = fmaxf(v.z - m, -80.0f);
        v.w = fmaxf(v.w - m, -80.0f);
        reinterpret_cast<float4*>(out)[i4] = v;
    }
}

// ---------------------------------------------------------------------------
// Fallback (fp32 vector path) if ws tiny.
// ---------------------------------------------------------------------------
namespace fb {
constexpr int TILE_F = 32;
constexpr int SPAN   = (TILE_F - 1) * NHOP + NDFT;
}

__global__ __launch_bounds__(256) void spec_main_fb(
    const float* __restrict__ x, const float* __restrict__ kr,
    const float* __restrict__ ki, float* __restrict__ out,
    unsigned int* __restrict__ wmax)
{
    __shared__ float xs[fb::SPAN];
    const int s   = blockIdx.x;
    const int f0  = blockIdx.y * fb::TILE_F;
    const int tid = threadIdx.x;
    const long sig_base = (long)s * LSRC;
    const int start = f0 * NHOP - PAD_L;
    for (int i = tid; i < fb::SPAN; i += 256) {
        const int p = start + i;
        xs[i] = (p >= 0 && p < LSRC) ? x[sig_base + p] : 0.0f;
    }
    __syncthreads();
    const int b0 = tid, b1 = tid + 256;
    float ar0[fb::TILE_F], ai0[fb::TILE_F], ar1[fb::TILE_F], ai1[fb::TILE_F];
    #pragma unroll
    for (int f = 0; f < fb::TILE_F; ++f) { ar0[f]=0.f; ai0[f]=0.f; ar1[f]=0.f; ai1[f]=0.f; }
    #pragma unroll 1
    for (int t = 0; t < NDFT; t += 4) {
        float br0[4], bq0[4], br1[4], bq1[4];
        #pragma unroll
        for (int j = 0; j < 4; ++j) {
            br0[j] = kr[(t + j) * NFILT + b0]; bq0[j] = ki[(t + j) * NFILT + b0];
            br1[j] = kr[(t + j) * NFILT + b1]; bq1[j] = ki[(t + j) * NFILT + b1];
        }
        #pragma unroll
        for (int f = 0; f < fb::TILE_F; ++f) {
            const float4 a = *reinterpret_cast<const float4*>(&xs[t + NHOP * f]);
            ar0[f]=fmaf(a.x,br0[0],ar0[f]); ar0[f]=fmaf(a.y,br0[1],ar0[f]);
            ar0[f]=fmaf(a.z,br0[2],ar0[f]); ar0[f]=fmaf(a.w,br0[3],ar0[f]);
            ai0[f]=fmaf(a.x,bq0[0],ai0[f]); ai0[f]=fmaf(a.y,bq0[1],ai0[f]);
            ai0[f]=fmaf(a.z,bq0[2],ai0[f]); ai0[f]=fmaf(a.w,bq0[3],ai0[f]);
            ar1[f]=fmaf(a.x,br1[0],ar1[f]); ar1[f]=fmaf(a.y,br1[1],ar1[f]);
            ar1[f]=fmaf(a.z,br1[2],ar1[f]); ar1[f]=fmaf(a.w,br1[3],ar1[f]);
            ai1[f]=fmaf(a.x,bq1[0],ai1[f]); ai1[f]=fmaf(a.y,bq1[1],ai1[f]);
            ai1[f]=fmaf(a.z,bq1[2],ai1[f]); ai1[f]=fmaf(a.w,bq1[3],ai1[f]);
        }
    }
    const int b = s >> 1, ch = s & 1;
    float lmax = -3.0e38f;
    #pragma unroll
    for (int f = 0; f < fb::TILE_F; ++f) {
        const int frame = f0 + f;
        const float p0 = ar0[f]*ar0[f] + ai0[f]*ai0[f];
        const float p1 = ar1[f]*ar1[f] + ai1[f]*ai1[f];
        const float d0 = 10.0f * log10f(fmaxf(p0, 1e-10f));
        const float d1 = 10.0f * log10f(fmaxf(p1, 1e-10f));
        lmax = fmaxf(lmax, fmaxf(d0, d1));
        out[((long)(b * NFILT + b0) * NFRAME + frame) * 2 + ch] = d0;
        out[((long)(b * NFILT + b1) * NFRAME + frame) * 2 + ch] = d1;
    }
    #pragma unroll
    for (int off = 32; off > 0; off >>= 1) lmax = fmaxf(lmax, __shfl_xor(lmax, off));
    if ((tid & 63) == 0) atomicMax(&wmax[b], f2key(lmax));
}

__global__ __launch_bounds__(256) void spec_nyq_fb(
    const float* __restrict__ x, const float* __restrict__ kr,
    const float* __restrict__ ki, float* __restrict__ out,
    unsigned int* __restrict__ wmax)
{
    const int gid   = blockIdx.x * 256 + threadIdx.x;
    const int s     = gid >> 10;
    const int frame = gid & 1023;
    const float* xp = x + (long)s * LSRC;
    const int start = frame * NHOP - PAD_L;
    float re = 0.f, im = 0.f;
    for (int t = 0; t < NDFT; ++t) {
        const int idx = start + t;
        const float a = (idx >= 0 && idx < LSRC) ? xp[idx] : 0.0f;
        re = fmaf(a, kr[t * NFILT + 512], re);
        im = fmaf(a, ki[t * NFILT + 512], im);
    }
    const float p = re * re + im * im;
    const float d = 10.0f * log10f(fmaxf(p, 1e-10f));
    const int b = s >> 1, ch = s & 1;
    out[((long)(b * NFILT + 512) * NFRAME + frame) * 2 + ch] = d;
    float lmax = d;
    #pragma unroll
    for (int off = 32; off > 0; off >>= 1) lmax = fmaxf(lmax, __shfl_xor(lmax, off));
    if ((threadIdx.x & 63) == 0) atomicMax(&wmax[b], f2key(lmax));
}

extern "C" void kernel_launch(void* const* d_in, const int* in_sizes, int n_in,
                              void* d_out, int out_size, void* d_ws, size_t ws_size,
                              hipStream_t stream) {
    const float* x  = (const float*)d_in[0];
    const float* kr = (const float*)d_in[1];
    const float* ki = (const float*)d_in[2];
    float* out = (float*)d_out;
    const long n4 = (long)out_size / 4;

    // folded tier: [wmax 128B][B2 2MB][sumH|sumL|diffH|diffL, nsig MB each]
    int nsig = 0;
    const int cands[4] = {64, 32, 16, 8};
    for (int c = 0; c < 4; ++c) {
        const size_t need = 128 + WSB2_BYTES + (size_t)cands[c] * 4 * 1048576;
        if (ws_size >= need) { nsig = cands[c]; break; }
    }

    if (nsig) {
        unsigned int* wmax   = (unsigned int*)d_ws;
        unsigned short* wsB2 = (unsigned short*)((char*)d_ws + 128);
        unsigned short* sH   = (unsigned short*)((char*)d_ws + 128 + WSB2_BYTES);
        const size_t pe = (size_t)nsig * PLANE_ELEMS_PER_SIG;
        unsigned short* sL = sH + pe;
        unsigned short* dH = sL + pe;
        unsigned short* dL = dH + pe;
        zero_ws<<<1, 64, 0, stream>>>(wmax);
        build_B2<<<128, 256, 0, stream>>>(kr, ki, wsB2);
        const int npass = 64 / nsig;
        for (int p = 0; p < npass; ++p) {
            fold_split<<<nsig * 256, 256, 0, stream>>>(x, sH, sL, dH, dL, p * nsig);
            spec_gemm2<<<nsig * 64, 512, 0, stream>>>(sH, sL, dH, dL, wsB2, out, wmax,
                                                      p * nsig, nsig);
        }
        spec_nyq<<<1024, 256, 0, stream>>>(x, kr, ki, out, wmax);
        finalize<<<2048, 256, 0, stream>>>(out, wmax, n4);
    } else if (ws_size >= WS_B_BYTES + 128) {
        unsigned short* wsB = (unsigned short*)d_ws;
        unsigned int* wmax  = (unsigned int*)((char*)d_ws + WS_B_BYTES);
        zero_ws<<<1, 64, 0, stream>>>(wmax);
        build_B<<<8 * KT1, 256, 0, stream>>>(kr, ki, wsB);
        spec_gemm_mid<<<dim3(512, 8), 256, 0, stream>>>(x, wsB, out, wmax);
        spec_nyq<<<1024, 256, 0, stream>>>(x, kr, ki, out, wmax);
        finalize<<<2048, 256, 0, stream>>>(out, wmax, n4);
    } else {
        unsigned int* wmax = (unsigned int*)d_ws;
        zero_ws<<<1, 64, 0, stream>>>(wmax);
        dim3 grid(64, NFRAME / fb::TILE_F);
        spec_main_fb<<<grid, 256, 0, stream>>>(x, kr, ki, out, wmax);
        spec_nyq_fb<<<(64 * NFRAME) / 256, 256, 0, stream>>>(x, kr, ki, out, wmax);
        finalize<<<2048, 256, 0, stream>>>(out, wmax, n4);
    }
}

// Round 15
// 567.667 us; speedup vs baseline: 1.0364x; 1.0364x over previous
//
#include <hip/hip_runtime.h>
#include <math.h>

namespace {
constexpr int NDFT   = 1024;
constexpr int NHOP   = 256;
constexpr int NFILT  = 513;
constexpr int LSRC   = 262144;
constexpr int NFRAME = 1024;
constexpr int PAD_L  = 384;
constexpr long PER_B = (long)NFILT * NFRAME * 2;

// ---- folded tier (K=512) ----
constexpr int KT2 = 16;               // K-tiles of 32 slots
constexpr int CHUNK_US = 8192;        // ushorts per (nt,kt) chunk = 16 KB
constexpr size_t WSB2_BYTES = (size_t)8 * KT2 * CHUNK_US * 2;   // 2 MiB
constexpr size_t PLANE_ELEMS_PER_SIG = 1024 * 512;              // 0.5M elems = 1 MiB

// ---- mid tier (r3 kernel, K=1024) ----
constexpr int KT1 = 32;
constexpr size_t WS_B_BYTES = (size_t)8 * KT1 * CHUNK_US * 2;   // 4 MiB
}

using short8 = __attribute__((ext_vector_type(8))) short;
using f32x4  = __attribute__((ext_vector_type(4))) float;

__device__ __forceinline__ unsigned int f2key(float f) {
    unsigned int u = __float_as_uint(f);
    return (u & 0x80000000u) ? ~u : (u | 0x80000000u);
}
__device__ __forceinline__ float key2f(unsigned int k) {
    return (k & 0x80000000u) ? __uint_as_float(k ^ 0x80000000u) : __uint_as_float(~k);
}
__device__ __forceinline__ unsigned short bf16rn(float v) {
    unsigned int u = __float_as_uint(v);
    return (unsigned short)((u + 0x7fffu + ((u >> 16) & 1u)) >> 16);
}

__global__ void zero_ws(unsigned int* __restrict__ w) {
    if (threadIdx.x < 32) w[threadIdx.x] = 0u;
}

// ---------------------------------------------------------------------------
// Fold prepass: for each frame f, slot s in [0,512):
//   s==0 : sum = diff = x[base+512]            (unpaired t=512 tap)
//   s>=1 : sum = x[base+s] + x[base+1024-s], diff = x[base+s] - x[base+1024-s]
// split each into hi/lo bf16 planes [frame][512]. One wave per frame.
// ---------------------------------------------------------------------------
__global__ __launch_bounds__(256) void fold_split(
    const float* __restrict__ x,
    unsigned short* __restrict__ sH, unsigned short* __restrict__ sL,
    unsigned short* __restrict__ dH, unsigned short* __restrict__ dL,
    int sig0)
{
    const int floc = blockIdx.x * 4 + (threadIdx.x >> 6);  // within-pass frame
    const int grp  = threadIdx.x & 63;                     // 8 slots each
    const int sig  = sig0 + (floc >> 10);
    const int fl   = floc & 1023;
    const long sbase = (long)sig * LSRC;
    const int st   = fl * NHOP - PAD_L;                    // mod 8 == 0
    const int s0   = grp * 8;

    const float xmid = x[sbase + st + 512];                // always in bounds

    float fw[8], bw[8];                                    // bw[j] = x2 for slot s0+j
    if (fl >= 2 && fl <= 1021) {
        const float4 a0 = *reinterpret_cast<const float4*>(x + sbase + st + s0);
        const float4 a1 = *reinterpret_cast<const float4*>(x + sbase + st + s0 + 4);
        fw[0]=a0.x; fw[1]=a0.y; fw[2]=a0.z; fw[3]=a0.w;
        fw[4]=a1.x; fw[5]=a1.y; fw[6]=a1.z; fw[7]=a1.w;
        const long q0 = sbase + st + 1017 - s0;            // q0-1 is 32B aligned
        const float4 b0 = *reinterpret_cast<const float4*>(x + q0 - 1);
        const float4 b1 = *reinterpret_cast<const float4*>(x + q0 + 3);
        const float  b2 = x[q0 + 7];
        const float va[8] = {b0.y, b0.z, b0.w, b1.x, b1.y, b1.z, b1.w, b2}; // va[i]=x[q0+i]
        #pragma unroll
        for (int j = 0; j < 8; ++j) bw[j] = va[7 - j];
    } else {
        #pragma unroll
        for (int j = 0; j < 8; ++j) {
            const int s = s0 + j;
            const int p1 = st + s;
            const int p2 = st + 1024 - s;
            fw[j] = ((unsigned)p1 < (unsigned)LSRC) ? x[sbase + p1] : 0.0f;
            bw[j] = ((unsigned)p2 < (unsigned)LSRC) ? x[sbase + p2] : 0.0f;
        }
    }

    union { unsigned short u[8]; uint4 v; } shv, slv, dhv, dlv;
    #pragma unroll
    for (int j = 0; j < 8; ++j) {
        float x1 = fw[j], x2 = bw[j];
        if (j == 0 && s0 == 0) { x1 = xmid; x2 = 0.0f; }
        const float sm = x1 + x2;
        const float df = x1 - x2;
        const unsigned short h1 = bf16rn(sm);
        shv.u[j] = h1;
        slv.u[j] = bf16rn(sm - __uint_as_float((unsigned int)h1 << 16));
        const unsigned short h2 = bf16rn(df);
        dhv.u[j] = h2;
        dlv.u[j] = bf16rn(df - __uint_as_float((unsigned int)h2 << 16));
    }
    const size_t wo = (size_t)floc * 512 + s0;
    *reinterpret_cast<uint4*>(sH + wo) = shv.v;
    *reinterpret_cast<uint4*>(sL + wo) = slv.v;
    *reinterpret_cast<uint4*>(dH + wo) = dhv.v;
    *reinterpret_cast<uint4*>(dL + wo) = dlv.v;
}

// ---------------------------------------------------------------------------
// Folded-B build: chunk per (nt,kt): rows n in [0,128): n<64 -> kr (cos) bin
// nt*64+n; n>=64 -> ki (sin) bin nt*64+n-64. Slot s = kt*32+c*8+i maps to
// DFT row t = (s==0) ? 512 : s. Hi/lo + XOR-swizzled 16 KB LDS-image chunks.
// ---------------------------------------------------------------------------
__global__ __launch_bounds__(256) void build_B2(const float* __restrict__ kr,
                                                const float* __restrict__ ki,
                                                unsigned short* __restrict__ wsB)
{
    const int nt = blockIdx.x >> 4;
    const int kt = blockIdx.x & 15;
    unsigned short* chunk = wsB + (size_t)blockIdx.x * CHUNK_US;
    const int col = threadIdx.x >> 1;        // 0..127
    const int h   = threadIdx.x & 1;
    const int bin = nt * 64 + (col & 63);
    const float* src = (col < 64) ? kr : ki;
    #pragma unroll
    for (int j = 0; j < 4; ++j) {
        const int sl = h * 4 + j;
        const int c  = sl & 3;
        union { unsigned short u[8]; uint4 v; } pk;
        #pragma unroll
        for (int i = 0; i < 8; ++i) {
            const int s = kt * 32 + c * 8 + i;
            const int t = (s == 0) ? 512 : s;
            const float v = src[t * NFILT + bin];
            const unsigned short hi = bf16rn(v);
            pk.u[i] = h ? bf16rn(v - __uint_as_float((unsigned int)hi << 16)) : hi;
        }
        *reinterpret_cast<uint4*>(&chunk[col * 64 + ((sl ^ (col & 7)) << 3)]) = pk.v;
    }
}

// ---------------------------------------------------------------------------
// Folded GEMM v3: block = 128 frames x 256 cols (2 nt subtiles), 16 waves
// (1024 thr). Intensity 96 FLOP/B (vs 64 at 128x128) -> compute-bound vs L2.
// Per wn (cos/sin): 8 waves, wave-tile 32x64 -> acc[2][4] = 32 AGPR.
// LDS: [2 buf][A 32 KB | B 32 KB] = 128 KB, DOUBLE-buffered: STAGE(kt+1)
// issued before COMPUTE(kt) -> stage latency hides under ~1850cy of MFMA;
// ONE barrier per kt. Staging: 4 gloads/wave (A 2 + B 2), per-lane
// pre-swizzled gather (r13-proven). Epilogue re^2 tile aliases buffers.
// ---------------------------------------------------------------------------
__global__ __launch_bounds__(1024, 1) void spec_gemm2(
    const unsigned short* __restrict__ sH, const unsigned short* __restrict__ sL,
    const unsigned short* __restrict__ dH, const unsigned short* __restrict__ dL,
    const unsigned short* __restrict__ wsB,
    float* __restrict__ out, unsigned int* __restrict__ wmax,
    int sig0, int nsig)
{
    __shared__ unsigned short smem[65536];  // 128 KB: [2][A0|A1|B0|B1]

    const int tid  = threadIdx.x;
    const int lane = tid & 63, w = tid >> 6;    // 16 waves
    const int wn  = w >> 3;                     // 0: cos/sum, 1: sin/diff
    const int aw  = w & 7;                      // wave within wn
    const int mq  = aw >> 1, nh = aw & 1;       // row-quarter (32), col-half (64)
    const int l15 = lane & 15, l16 = lane >> 4;

    const int phys = blockIdx.x;                // 0 .. nsig*32-1
    const int xcd  = phys & 7, slot = phys >> 3;
    const int ntp  = slot & 3;                  // nt pair: cols ntp*128..+128
    const int mt   = xcd * nsig + (slot >> 2);  // within-pass mt
    const int sig  = sig0 + (mt >> 3);
    const int f0   = (mt & 7) * 128;            // within-signal frame base

    const unsigned short* __restrict__ pH = wn ? dH : sH;
    const unsigned short* __restrict__ pL = wn ? dL : sL;

    // A gather lane constants: lane = (rl row-in-8, jj 16B-slot); LDS pos jj
    // of row r holds global slot q = jj ^ (r&7); q<4 -> hi octet q, else lo.
    const int rl = lane >> 3, jj = lane & 7;
    const int q  = jj ^ rl;
    const unsigned short* apl = (q < 4) ? pH : pL;
    const unsigned short* agsrc[2];
    #pragma unroll
    for (int i = 0; i < 2; ++i)
        agsrc[i] = apl + (size_t)(mt * 128 + aw * 16 + i * 8 + rl) * 512 + (q & 3) * 8;

    // B gather: wave stages cols c = aw*16 + i*8 + rl of its wn region.
    // col c (0..127) -> chunk nt = ntp*2 + (c>>6), col-in-chunk wn*64+(c&63).
    const unsigned short* bgsrc[2];
    #pragma unroll
    for (int i = 0; i < 2; ++i) {
        const int c = aw * 16 + i * 8 + rl;
        const int ntg = ntp * 2 + (c >> 6);
        bgsrc[i] = wsB + (size_t)(ntg * KT2) * CHUNK_US
                 + (wn * 64 + (c & 63)) * 64 + jj * 8;
    }

    f32x4 acc[2][4];
    #pragma unroll
    for (int i = 0; i < 2; ++i)
        #pragma unroll
        for (int j = 0; j < 4; ++j)
            #pragma unroll
            for (int r = 0; r < 4; ++r) acc[i][j][r] = 0.0f;

    // buffer layout (ushort offsets): base = buf*32768;
    // A_wn = base + wn*8192; B_wn = base + 16384 + wn*8192.
    #define STAGE(ktv, buf)                                                    \
        {                                                                      \
            unsigned short* abase_l = smem + (buf) * 32768 + wn * 8192 + aw * 1024; \
            _Pragma("unroll")                                                  \
            for (int i = 0; i < 2; ++i)                                        \
                __builtin_amdgcn_global_load_lds(                              \
                    (const __attribute__((address_space(1))) unsigned int*)(agsrc[i] + (size_t)(ktv) * 32), \
                    (__attribute__((address_space(3))) unsigned int*)(abase_l + i * 512), \
                    16, 0, 0);                                                 \
            unsigned short* bbase_l = smem + (buf) * 32768 + 16384 + wn * 8192 + aw * 1024; \
            _Pragma("unroll")                                                  \
            for (int i = 0; i < 2; ++i)                                        \
                __builtin_amdgcn_global_load_lds(                              \
                    (const __attribute__((address_space(1))) unsigned int*)(bgsrc[i] + (size_t)(ktv) * CHUNK_US), \
                    (__attribute__((address_space(3))) unsigned int*)(bbase_l + i * 512), \
                    16, 0, 0);                                                 \
        }

    #define COMPUTE(buf)                                                       \
        {                                                                      \
            const unsigned short* Areg = smem + (buf) * 32768 + wn * 8192;     \
            const unsigned short* Breg = smem + (buf) * 32768 + 16384 + wn * 8192; \
            short8 ah[2], al[2], bh[4], bl[4];                                 \
            _Pragma("unroll")                                                  \
            for (int mf = 0; mf < 2; ++mf) {                                   \
                const int row = mq * 32 + mf * 16 + l15;                       \
                const unsigned short* ab = Areg + row * 64;                    \
                ah[mf] = *reinterpret_cast<const short8*>(ab + ((l16 ^ (row & 7)) << 3));        \
                al[mf] = *reinterpret_cast<const short8*>(ab + (((4 + l16) ^ (row & 7)) << 3));  \
            }                                                                  \
            _Pragma("unroll")                                                  \
            for (int nf = 0; nf < 4; ++nf) {                                   \
                const int c = nh * 64 + nf * 16 + l15;                         \
                const unsigned short* bb = Breg + c * 64;                      \
                bh[nf] = *reinterpret_cast<const short8*>(bb + ((l16 ^ (c & 7)) << 3));          \
                bl[nf] = *reinterpret_cast<const short8*>(bb + (((4 + l16) ^ (c & 7)) << 3));    \
            }                                                                  \
            __builtin_amdgcn_s_setprio(1);                                     \
            _Pragma("unroll")                                                  \
            for (int nf = 0; nf < 4; ++nf)                                     \
                _Pragma("unroll")                                              \
                for (int mf = 0; mf < 2; ++mf) {                               \
                    acc[mf][nf] = __builtin_amdgcn_mfma_f32_16x16x32_bf16(ah[mf], bh[nf], acc[mf][nf], 0, 0, 0); \
                    acc[mf][nf] = __builtin_amdgcn_mfma_f32_16x16x32_bf16(al[mf], bh[nf], acc[mf][nf], 0, 0, 0); \
                    acc[mf][nf] = __builtin_amdgcn_mfma_f32_16x16x32_bf16(ah[mf], bl[nf], acc[mf][nf], 0, 0, 0); \
                }                                                              \
            __builtin_amdgcn_s_setprio(0);                                     \
        }

    STAGE(0, 0)
    __syncthreads();

    #pragma unroll 1
    for (int kt = 0; kt < KT2; ++kt) {
        if (kt + 1 < KT2) STAGE(kt + 1, (kt + 1) & 1)
        COMPUTE(kt & 1)
        __syncthreads();
    }
    #undef STAGE
    #undef COMPUTE

    // ---- epilogue: wn=0 writes re^2 (bf16) into smem (aliases buffers);
    //      wn=1 combines re^2+im^2, dB, store + per-batch max ----
    if (wn == 0) {
        #pragma unroll
        for (int mf = 0; mf < 2; ++mf)
            #pragma unroll
            for (int nf = 0; nf < 4; ++nf) {
                const int c = nh * 64 + nf * 16 + l15;
                #pragma unroll
                for (int r = 0; r < 4; ++r) {
                    const int row = mq * 32 + mf * 16 + l16 * 4 + r;
                    const float v = acc[mf][nf][r];
                    smem[row * 132 + c] = bf16rn(v * v);
                }
            }
    }
    __syncthreads();
    if (wn == 1) {
        const int batch = sig >> 1, ch = sig & 1;
        float lmax = -3.0e38f;
        #pragma unroll
        for (int mf = 0; mf < 2; ++mf)
            #pragma unroll
            for (int nf = 0; nf < 4; ++nf) {
                const int c = nh * 64 + nf * 16 + l15;
                const int bin = ntp * 128 + c;
                #pragma unroll
                for (int r = 0; r < 4; ++r) {
                    const int row = mq * 32 + mf * 16 + l16 * 4 + r;
                    const float v = acc[mf][nf][r];
                    const float re2 = __uint_as_float((unsigned int)smem[row * 132 + c] << 16);
                    const float p = re2 + v * v;
                    const float d = 10.0f * log10f(fmaxf(p, 1e-10f));
                    const int frame = f0 + row;
                    out[((long)(batch * NFILT + bin) * NFRAME + frame) * 2 + ch] = d;
                    lmax = fmaxf(lmax, d);
                }
            }
        #pragma unroll
        for (int off = 32; off > 0; off >>= 1) lmax = fmaxf(lmax, __shfl_xor(lmax, off));
        if (lane == 0) atomicMax(&wmax[batch], f2key(lmax));
    }
}

// ---------------------------------------------------------------------------
// Mid-tier GEMM (round-3 proven kernel, K=1024, LDS-staged A) for small ws.
// ---------------------------------------------------------------------------
__global__ __launch_bounds__(256) void build_B(const float* __restrict__ kr,
                                               const float* __restrict__ ki,
                                               unsigned short* __restrict__ wsB)
{
    const int nt = blockIdx.x >> 5;
    const int kt = blockIdx.x & 31;
    unsigned short* chunk = wsB + (size_t)blockIdx.x * CHUNK_US;
    const int col = threadIdx.x >> 1;
    const int h   = threadIdx.x & 1;
    const int bin = nt * 64 + (col >> 1);
    const float* src = (col & 1) ? ki : kr;
    #pragma unroll
    for (int j = 0; j < 4; ++j) {
        const int sl = h * 4 + j;
        const int c  = sl & 3;
        union { unsigned short u[8]; uint4 v; } pk;
        #pragma unroll
        for (int i = 0; i < 8; ++i) {
            const int t = kt * 32 + c * 8 + i;
            const float v = src[t * NFILT + bin];
            const unsigned short hi = bf16rn(v);
            pk.u[i] = h ? bf16rn(v - __uint_as_float((unsigned int)hi << 16)) : hi;
        }
        *reinterpret_cast<uint4*>(&chunk[col * 64 + ((sl ^ (col & 7)) << 3)]) = pk.v;
    }
}

__global__ __launch_bounds__(256, 2) void spec_gemm_mid(
    const float* __restrict__ x, const unsigned short* __restrict__ wsB,
    float* __restrict__ out, unsigned int* __restrict__ wmax)
{
    __shared__ unsigned short Ad[2][128][64];
    __shared__ unsigned short Bd[2][128][64];

    const int tid  = threadIdx.x;
    const int lane = tid & 63, w = tid >> 6;
    const int wm = w >> 1, wn = w & 1;
    const int l15 = lane & 15, l16 = lane >> 4;
    const int mt = blockIdx.x, nt = blockIdx.y;
    const int sig = mt >> 3, f0 = (mt & 7) * 128;
    const long sb = (long)sig * LSRC;

    const int arow = tid >> 1, ac2 = tid & 1;
    const int abase_p = (f0 + arow) * NHOP - PAD_L + ac2 * 16;
    const unsigned short* bchunks = wsB + (size_t)nt * KT1 * CHUNK_US;

    f32x4 acc[4][4];
    #pragma unroll
    for (int i = 0; i < 4; ++i)
        #pragma unroll
        for (int j = 0; j < 4; ++j)
            #pragma unroll
            for (int r = 0; r < 4; ++r) acc[i][j][r] = 0.0f;

    float va[16];

    #define LOAD_A(ktv)                                                        \
        {                                                                      \
            const int p0 = abase_p + (ktv) * 32;                               \
            if (p0 >= 0 && p0 + 16 <= LSRC) {                                  \
                *reinterpret_cast<float4*>(&va[0])  = *reinterpret_cast<const float4*>(x + sb + p0);      \
                *reinterpret_cast<float4*>(&va[4])  = *reinterpret_cast<const float4*>(x + sb + p0 + 4);  \
                *reinterpret_cast<float4*>(&va[8])  = *reinterpret_cast<const float4*>(x + sb + p0 + 8);  \
                *reinterpret_cast<float4*>(&va[12]) = *reinterpret_cast<const float4*>(x + sb + p0 + 12); \
            } else {                                                           \
                _Pragma("unroll")                                              \
                for (int i = 0; i < 16; ++i) {                                 \
                    const int p = p0 + i;                                      \
                    va[i] = (p >= 0 && p < LSRC) ? x[sb + p] : 0.0f;           \
                }                                                              \
            }                                                                  \
        }

    #define LOAD_B(ktv, nb)                                                    \
        {                                                                      \
            const char* g = (const char*)(bchunks + (size_t)(ktv) * CHUNK_US); \
            char* l = (char*)&Bd[nb][0][0];                                    \
            _Pragma("unroll")                                                  \
            for (int i = 0; i < 4; ++i) {                                      \
                const int off = i * 4096 + w * 1024;                           \
                __builtin_amdgcn_global_load_lds(                              \
                    (const __attribute__((address_space(1))) unsigned int*)(g + off + lane * 16), \
                    (__attribute__((address_space(3))) unsigned int*)(l + off), \
                    16, 0, 0);                                                 \
            }                                                                  \
        }

    #define WRITE_A(nb)                                                       \
        {                                                                      \
            unsigned short* ab = &Ad[nb][arow][0];                             \
            _Pragma("unroll")                                                  \
            for (int j = 0; j < 2; ++j) {                                      \
                union { unsigned short u[8]; uint4 v; } hv, lv;                \
                _Pragma("unroll")                                              \
                for (int i = 0; i < 8; ++i) {                                  \
                    const float vv = va[j * 8 + i];                            \
                    const unsigned short hi = bf16rn(vv);                      \
                    hv.u[i] = hi;                                              \
                    lv.u[i] = bf16rn(vv - __uint_as_float((unsigned int)hi << 16)); \
                }                                                              \
                const int c = ac2 * 2 + j;                                     \
                *reinterpret_cast<uint4*>(ab + (((c) ^ (arow & 7)) << 3))     = hv.v; \
                *reinterpret_cast<uint4*>(ab + (((4 + c) ^ (arow & 7)) << 3)) = lv.v; \
            }                                                                  \
        }

    LOAD_A(0)
    LOAD_B(0, 0)
    WRITE_A(0)
    __syncthreads();

    #pragma unroll 1
    for (int kt = 0; kt < KT1; ++kt) {
        const int cur = kt & 1, nxt = cur ^ 1;
        const bool pf = (kt + 1 < KT1);
        if (pf) {
            LOAD_A(kt + 1)
            LOAD_B(kt + 1, nxt)
        }
        short8 ah[4], al[4];
        #pragma unroll
        for (int mf = 0; mf < 4; ++mf) {
            const int row = wm * 64 + mf * 16 + l15;
            const unsigned short* ab = &Ad[cur][row][0];
            ah[mf] = *reinterpret_cast<const short8*>(ab + ((l16 ^ (row & 7)) << 3));
            al[mf] = *reinterpret_cast<const short8*>(ab + (((4 + l16) ^ (row & 7)) << 3));
        }
        __builtin_amdgcn_s_setprio(1);
        #pragma unroll
        for (int nf = 0; nf < 4; ++nf) {
            const int col = wn * 64 + nf * 16 + l15;
            const unsigned short* bb = &Bd[cur][col][0];
            const short8 bh = *reinterpret_cast<const short8*>(bb + ((l16 ^ (col & 7)) << 3));
            const short8 bl = *reinterpret_cast<const short8*>(bb + (((4 + l16) ^ (col & 7)) << 3));
            #pragma unroll
            for (int mf = 0; mf < 4; ++mf) {
                acc[mf][nf] = __builtin_amdgcn_mfma_f32_16x16x32_bf16(ah[mf], bh, acc[mf][nf], 0, 0, 0);
                acc[mf][nf] = __builtin_amdgcn_mfma_f32_16x16x32_bf16(al[mf], bh, acc[mf][nf], 0, 0, 0);
                acc[mf][nf] = __builtin_amdgcn_mfma_f32_16x16x32_bf16(ah[mf], bl, acc[mf][nf], 0, 0, 0);
            }
        }
        __builtin_amdgcn_s_setprio(0);
        if (pf) WRITE_A(nxt)
        __syncthreads();
    }
    #undef LOAD_A
    #undef LOAD_B
    #undef WRITE_A

    const int batch = sig >> 1, ch = sig & 1;
    float lmax = -3.0e38f;
    #pragma unroll
    for (int mf = 0; mf < 4; ++mf)
        #pragma unroll
        for (int nf = 0; nf < 4; ++nf) {
            const int col = nt * 128 + wn * 64 + nf * 16 + l15;
            const int bin = col >> 1;
            #pragma unroll
            for (int r = 0; r < 4; ++r) {
                const float v  = acc[mf][nf][r];
                const float sq = v * v;
                const float p  = sq + __shfl_xor(sq, 1);
                if (!(lane & 1)) {
                    const int frame = f0 + wm * 64 + mf * 16 + l16 * 4 + r;
                    const float d = 10.0f * log10f(fmaxf(p, 1e-10f));
                    out[((long)(batch * NFILT + bin) * NFRAME + frame) * 2 + ch] = d;
                    lmax = fmaxf(lmax, d);
                }
            }
        }
    #pragma unroll
    for (int off = 32; off > 0; off >>= 1) lmax = fmaxf(lmax, __shfl_xor(lmax, off));
    if (lane == 0) atomicMax(&wmax[batch], f2key(lmax));
}

// ---------------------------------------------------------------------------
// Nyquist bin (512): block = 1 signal x 64 frames, x + coeffs staged in LDS.
// ---------------------------------------------------------------------------
__global__ __launch_bounds__(256, 2) void spec_nyq(
    const float* __restrict__ x, const float* __restrict__ kr,
    const float* __restrict__ ki, float* __restrict__ out,
    unsigned int* __restrict__ wmax)
{
    __shared__ float xs[17152];
    __shared__ float kc[1024], ks[1024];
    const int sig = blockIdx.x >> 4, ft = blockIdx.x & 15;
    const int f0 = ft * 64;
    const long sb = (long)sig * LSRC;
    const int start = f0 * NHOP - PAD_L;
    for (int i = threadIdx.x; i < 17152; i += 256) {
        const int p = start + i;
        xs[i] = (p >= 0 && p < LSRC) ? x[sb + p] : 0.0f;
    }
    for (int t = threadIdx.x; t < 1024; t += 256) {
        kc[t] = kr[t * NFILT + 512];
        ks[t] = ki[t * NFILT + 512];
    }
    __syncthreads();
    const int fr = threadIdx.x >> 2, q = threadIdx.x & 3;
    const int rot = ((fr + q) & 7) * 4;
    float re = 0.0f, im = 0.0f;
    #pragma unroll 4
    for (int j = 0; j < 256; j += 4) {
        const int je = (j + rot) & 255;
        const float4 a = *reinterpret_cast<const float4*>(&xs[fr * 256 + q * 256 + je]);
        const float4 c = *reinterpret_cast<const float4*>(&kc[q * 256 + je]);
        const float4 s = *reinterpret_cast<const float4*>(&ks[q * 256 + je]);
        re = fmaf(a.x, c.x, re); re = fmaf(a.y, c.y, re);
        re = fmaf(a.z, c.z, re); re = fmaf(a.w, c.w, re);
        im = fmaf(a.x, s.x, im); im = fmaf(a.y, s.y, im);
        im = fmaf(a.z, s.z, im); im = fmaf(a.w, s.w, im);
    }
    re += __shfl_xor(re, 1); re += __shfl_xor(re, 2);
    im += __shfl_xor(im, 1); im += __shfl_xor(im, 2);
    const int batch = sig >> 1, ch = sig & 1;
    float lmax = -3.0e38f;
    if (q == 0) {
        const float p = re * re + im * im;
        const float d = 10.0f * log10f(fmaxf(p, 1e-10f));
        out[((long)(batch * NFILT + 512) * NFRAME + (f0 + fr)) * 2 + ch] = d;
        lmax = d;
    }
    #pragma unroll
    for (int off = 32; off > 0; off >>= 1) lmax = fmaxf(lmax, __shfl_xor(lmax, off));
    if ((threadIdx.x & 63) == 0) atomicMax(&wmax[batch], f2key(lmax));
}

__global__ __launch_bounds__(256) void finalize(
    float* __restrict__ out, const unsigned int* __restrict__ wmax, long n4)
{
    const long stride = (long)gridDim.x * 256;
    for (long i4 = blockIdx.x * 256L + threadIdx.x; i4 < n4; i4 += stride) {
        const long i = i4 * 4;
        const int b  = (int)(i / PER_B);
        const float m = key2f(wmax[b]);
        float4 v = reinterpret_cast<float4*>(out)[i4];
        v.x = fmaxf(v.x - m, -80.0f);
        v.y = fmaxf(v.y - m, -80.0f);
        v.z = fmaxf(v.z - m, -80.0f);
        v.w = fmaxf(v.w - m, -80.0f);
        reinterpret_cast<float4*>(out)[i4] = v;
    }
}

// ---------------------------------------------------------------------------
// Fallback (fp32 vector path) if ws tiny.
// ---------------------------------------------------------------------------
namespace fb {
constexpr int TILE_F = 32;
constexpr int SPAN   = (TILE_F - 1) * NHOP + NDFT;
}

__global__ __launch_bounds__(256) void spec_main_fb(
    const float* __restrict__ x, const float* __restrict__ kr,
    const float* __restrict__ ki, float* __restrict__ out,
    unsigned int* __restrict__ wmax)
{
    __shared__ float xs[fb::SPAN];
    const int s   = blockIdx.x;
    const int f0  = blockIdx.y * fb::TILE_F;
    const int tid = threadIdx.x;
    const long sig_base = (long)s * LSRC;
    const int start = f0 * NHOP - PAD_L;
    for (int i = tid; i < fb::SPAN; i += 256) {
        const int p = start + i;
        xs[i] = (p >= 0 && p < LSRC) ? x[sig_base + p] : 0.0f;
    }
    __syncthreads();
    const int b0 = tid, b1 = tid + 256;
    float ar0[fb::TILE_F], ai0[fb::TILE_F], ar1[fb::TILE_F], ai1[fb::TILE_F];
    #pragma unroll
    for (int f = 0; f < fb::TILE_F; ++f) { ar0[f]=0.f; ai0[f]=0.f; ar1[f]=0.f; ai1[f]=0.f; }
    #pragma unroll 1
    for (int t = 0; t < NDFT; t += 4) {
        float br0[4], bq0[4], br1[4], bq1[4];
        #pragma unroll
        for (int j = 0; j < 4; ++j) {
            br0[j] = kr[(t + j) * NFILT + b0]; bq0[j] = ki[(t + j) * NFILT + b0];
            br1[j] = kr[(t + j) * NFILT + b1]; bq1[j] = ki[(t + j) * NFILT + b1];
        }
        #pragma unroll
        for (int f = 0; f < fb::TILE_F; ++f) {
            const float4 a = *reinterpret_cast<const float4*>(&xs[t + NHOP * f]);
            ar0[f]=fmaf(a.x,br0[0],ar0[f]); ar0[f]=fmaf(a.y,br0[1],ar0[f]);
            ar0[f]=fmaf(a.z,br0[2],ar0[f]); ar0[f]=fmaf(a.w,br0[3],ar0[f]);
            ai0[f]=fmaf(a.x,bq0[0],ai0[f]); ai0[f]=fmaf(a.y,bq0[1],ai0[f]);
            ai0[f]=fmaf(a.z,bq0[2],ai0[f]); ai0[f]=fmaf(a.w,bq0[3],ai0[f]);
            ar1[f]=fmaf(a.x,br1[0],ar1[f]); ar1[f]=fmaf(a.y,br1[1],ar1[f]);
            ar1[f]=fmaf(a.z,br1[2],ar1[f]); ar1[f]=fmaf(a.w,br1[3],ar1[f]);
            ai1[f]=fmaf(a.x,bq1[0],ai1[f]); ai1[f]=fmaf(a.y,bq1[1],ai1[f]);
            ai1[f]=fmaf(a.z,bq1[2],ai1[f]); ai1[f]=fmaf(a.w,bq1[3],ai1[f]);
        }
    }
    const int b = s >> 1, ch = s & 1;
    float lmax = -3.0e38f;
    #pragma unroll
    for (int f = 0; f < fb::TILE_F; ++f) {
        const int frame = f0 + f;
        const float p0 = ar0[f]*ar0[f] + ai0[f]*ai0[f];
        const float p1 = ar1[f]*ar1[f] + ai1[f]*ai1[f];
        const float d0 = 10.0f * log10f(fmaxf(p0, 1e-10f));
        const float d1 = 10.0f * log10f(fmaxf(p1, 1e-10f));
        lmax = fmaxf(lmax, fmaxf(d0, d1));
        out[((long)(b * NFILT + b0) * NFRAME + frame) * 2 + ch] = d0;
        out[((long)(b * NFILT + b1) * NFRAME + frame) * 2 + ch] = d1;
    }
    #pragma unroll
    for (int off = 32; off > 0; off >>= 1) lmax = fmaxf(lmax, __shfl_xor(lmax, off));
    if ((tid & 63) == 0) atomicMax(&wmax[b], f2key(lmax));
}

__global__ __launch_bounds__(256) void spec_nyq_fb(
    const float* __restrict__ x, const float* __restrict__ kr,
    const float* __restrict__ ki, float* __restrict__ out,
    unsigned int* __restrict__ wmax)
{
    const int gid   = blockIdx.x * 256 + threadIdx.x;
    const int s     = gid >> 10;
    const int frame = gid & 1023;
    const float* xp = x + (long)s * LSRC;
    const int start = frame * NHOP - PAD_L;
    float re = 0.f, im = 0.f;
    for (int t = 0; t < NDFT; ++t) {
        const int idx = start + t;
        const float a = (idx >= 0 && idx < LSRC) ? xp[idx] : 0.0f;
        re = fmaf(a, kr[t * NFILT + 512], re);
        im = fmaf(a, ki[t * NFILT + 512], im);
    }
    const float p = re * re + im * im;
    const float d = 10.0f * log10f(fmaxf(p, 1e-10f));
    const int b = s >> 1, ch = s & 1;
    out[((long)(b * NFILT + 512) * NFRAME + frame) * 2 + ch] = d;
    float lmax = d;
    #pragma unroll
    for (int off = 32; off > 0; off >>= 1) lmax = fmaxf(lmax, __shfl_xor(lmax, off));
    if ((threadIdx.x & 63) == 0) atomicMax(&wmax[b], f2key(lmax));
}

extern "C" void kernel_launch(void* const* d_in, const int* in_sizes, int n_in,
                              void* d_out, int out_size, void* d_ws, size_t ws_size,
                              hipStream_t stream) {
    const float* x  = (const float*)d_in[0];
    const float* kr = (const float*)d_in[1];
    const float* ki = (const float*)d_in[2];
    float* out = (float*)d_out;
    const long n4 = (long)out_size / 4;

    // folded tier: [wmax 128B][B2 2MB][sumH|sumL|diffH|diffL, nsig MB each]
    int nsig = 0;
    const int cands[4] = {64, 32, 16, 8};
    for (int c = 0; c < 4; ++c) {
        const size_t need = 128 + WSB2_BYTES + (size_t)cands[c] * 4 * 1048576;
        if (ws_size >= need) { nsig = cands[c]; break; }
    }

    if (nsig) {
        unsigned int* wmax   = (unsigned int*)d_ws;
        unsigned short* wsB2 = (unsigned short*)((char*)d_ws + 128);
        unsigned short* sH   = (unsigned short*)((char*)d_ws + 128 + WSB2_BYTES);
        const size_t pe = (size_t)nsig * PLANE_ELEMS_PER_SIG;
        unsigned short* sL = sH + pe;
        unsigned short* dH = sL + pe;
        unsigned short* dL = dH + pe;
        zero_ws<<<1, 64, 0, stream>>>(wmax);
        build_B2<<<128, 256, 0, stream>>>(kr, ki, wsB2);
        const int npass = 64 / nsig;
        for (int p = 0; p < npass; ++p) {
            fold_split<<<nsig * 256, 256, 0, stream>>>(x, sH, sL, dH, dL, p * nsig);
            spec_gemm2<<<nsig * 32, 1024, 0, stream>>>(sH, sL, dH, dL, wsB2, out, wmax,
                                                       p * nsig, nsig);
        }
        spec_nyq<<<1024, 256, 0, stream>>>(x, kr, ki, out, wmax);
        finalize<<<2048, 256, 0, stream>>>(out, wmax, n4);
    } else if (ws_size >= WS_B_BYTES + 128) {
        unsigned short* wsB = (unsigned short*)d_ws;
        unsigned int* wmax  = (unsigned int*)((char*)d_ws + WS_B_BYTES);
        zero_ws<<<1, 64, 0, stream>>>(wmax);
        build_B<<<8 * KT1, 256, 0, stream>>>(kr, ki, wsB);
        spec_gemm_mid<<<dim3(512, 8), 256, 0, stream>>>(x, wsB, out, wmax);
        spec_nyq<<<1024, 256, 0, stream>>>(x, kr, ki, out, wmax);
        finalize<<<2048, 256, 0, stream>>>(out, wmax, n4);
    } else {
        unsigned int* wmax = (unsigned int*)d_ws;
        zero_ws<<<1, 64, 0, stream>>>(wmax);
        dim3 grid(64, NFRAME / fb::TILE_F);
        spec_main_fb<<<grid, 256, 0, stream>>>(x, kr, ki, out, wmax);
        spec_nyq_fb<<<(64 * NFRAME) / 256, 256, 0, stream>>>(x, kr, ki, out, wmax);
        finalize<<<2048, 256, 0, stream>>>(out, wmax, n4);
    }
}

// Round 16
// 527.322 us; speedup vs baseline: 1.1157x; 1.0765x over previous
//
#include <hip/hip_runtime.h>
#include <math.h>

namespace {
constexpr int NDFT   = 1024;
constexpr int NHOP   = 256;
constexpr int NFILT  = 513;
constexpr int LSRC   = 262144;
constexpr int NFRAME = 1024;
constexpr int PAD_L  = 384;
constexpr long PER_B = (long)NFILT * NFRAME * 2;

// ---- folded tier (K=512) ----
constexpr int KT2 = 16;               // K-tiles of 32 slots
constexpr int CHUNK_US = 8192;        // ushorts per (nt,kt) chunk = 16 KB
constexpr size_t WSB2_BYTES = (size_t)8 * KT2 * CHUNK_US * 2;   // 2 MiB
constexpr size_t PLANE_ELEMS_PER_SIG = 1024 * 512;              // 0.5M elems = 1 MiB

// ---- mid tier (r3 kernel, K=1024) ----
constexpr int KT1 = 32;
constexpr size_t WS_B_BYTES = (size_t)8 * KT1 * CHUNK_US * 2;   // 4 MiB
}

using short8 = __attribute__((ext_vector_type(8))) short;
using f32x4  = __attribute__((ext_vector_type(4))) float;

__device__ __forceinline__ unsigned int f2key(float f) {
    unsigned int u = __float_as_uint(f);
    return (u & 0x80000000u) ? ~u : (u | 0x80000000u);
}
__device__ __forceinline__ float key2f(unsigned int k) {
    return (k & 0x80000000u) ? __uint_as_float(k ^ 0x80000000u) : __uint_as_float(~k);
}
__device__ __forceinline__ unsigned short bf16rn(float v) {
    unsigned int u = __float_as_uint(v);
    return (unsigned short)((u + 0x7fffu + ((u >> 16) & 1u)) >> 16);
}

__global__ void zero_ws(unsigned int* __restrict__ w) {
    if (threadIdx.x < 32) w[threadIdx.x] = 0u;
}

// ---------------------------------------------------------------------------
// Fold prepass: for each frame f, slot s in [0,512):
//   s==0 : sum = diff = x[base+512]            (unpaired t=512 tap)
//   s>=1 : sum = x[base+s] + x[base+1024-s], diff = x[base+s] - x[base+1024-s]
// split each into hi/lo bf16 planes [frame][512]. One wave per frame.
// ---------------------------------------------------------------------------
__global__ __launch_bounds__(256) void fold_split(
    const float* __restrict__ x,
    unsigned short* __restrict__ sH, unsigned short* __restrict__ sL,
    unsigned short* __restrict__ dH, unsigned short* __restrict__ dL,
    int sig0)
{
    const int floc = blockIdx.x * 4 + (threadIdx.x >> 6);  // within-pass frame
    const int grp  = threadIdx.x & 63;                     // 8 slots each
    const int sig  = sig0 + (floc >> 10);
    const int fl   = floc & 1023;
    const long sbase = (long)sig * LSRC;
    const int st   = fl * NHOP - PAD_L;                    // mod 8 == 0
    const int s0   = grp * 8;

    const float xmid = x[sbase + st + 512];                // always in bounds

    float fw[8], bw[8];                                    // bw[j] = x2 for slot s0+j
    if (fl >= 2 && fl <= 1021) {
        const float4 a0 = *reinterpret_cast<const float4*>(x + sbase + st + s0);
        const float4 a1 = *reinterpret_cast<const float4*>(x + sbase + st + s0 + 4);
        fw[0]=a0.x; fw[1]=a0.y; fw[2]=a0.z; fw[3]=a0.w;
        fw[4]=a1.x; fw[5]=a1.y; fw[6]=a1.z; fw[7]=a1.w;
        const long q0 = sbase + st + 1017 - s0;            // q0-1 is 32B aligned
        const float4 b0 = *reinterpret_cast<const float4*>(x + q0 - 1);
        const float4 b1 = *reinterpret_cast<const float4*>(x + q0 + 3);
        const float  b2 = x[q0 + 7];
        const float va[8] = {b0.y, b0.z, b0.w, b1.x, b1.y, b1.z, b1.w, b2}; // va[i]=x[q0+i]
        #pragma unroll
        for (int j = 0; j < 8; ++j) bw[j] = va[7 - j];
    } else {
        #pragma unroll
        for (int j = 0; j < 8; ++j) {
            const int s = s0 + j;
            const int p1 = st + s;
            const int p2 = st + 1024 - s;
            fw[j] = ((unsigned)p1 < (unsigned)LSRC) ? x[sbase + p1] : 0.0f;
            bw[j] = ((unsigned)p2 < (unsigned)LSRC) ? x[sbase + p2] : 0.0f;
        }
    }

    union { unsigned short u[8]; uint4 v; } shv, slv, dhv, dlv;
    #pragma unroll
    for (int j = 0; j < 8; ++j) {
        float x1 = fw[j], x2 = bw[j];
        if (j == 0 && s0 == 0) { x1 = xmid; x2 = 0.0f; }
        const float sm = x1 + x2;
        const float df = x1 - x2;
        const unsigned short h1 = bf16rn(sm);
        shv.u[j] = h1;
        slv.u[j] = bf16rn(sm - __uint_as_float((unsigned int)h1 << 16));
        const unsigned short h2 = bf16rn(df);
        dhv.u[j] = h2;
        dlv.u[j] = bf16rn(df - __uint_as_float((unsigned int)h2 << 16));
    }
    const size_t wo = (size_t)floc * 512 + s0;
    *reinterpret_cast<uint4*>(sH + wo) = shv.v;
    *reinterpret_cast<uint4*>(sL + wo) = slv.v;
    *reinterpret_cast<uint4*>(dH + wo) = dhv.v;
    *reinterpret_cast<uint4*>(dL + wo) = dlv.v;
}

// ---------------------------------------------------------------------------
// Folded-B build: chunk per (nt,kt): rows n in [0,128): n<64 -> kr (cos) bin
// nt*64+n; n>=64 -> ki (sin) bin nt*64+n-64. Slot s = kt*32+c*8+i maps to
// DFT row t = (s==0) ? 512 : s. Hi/lo + XOR-swizzled 16 KB LDS-image chunks.
// ---------------------------------------------------------------------------
__global__ __launch_bounds__(256) void build_B2(const float* __restrict__ kr,
                                                const float* __restrict__ ki,
                                                unsigned short* __restrict__ wsB)
{
    const int nt = blockIdx.x >> 4;
    const int kt = blockIdx.x & 15;
    unsigned short* chunk = wsB + (size_t)blockIdx.x * CHUNK_US;
    const int col = threadIdx.x >> 1;        // 0..127
    const int h   = threadIdx.x & 1;
    const int bin = nt * 64 + (col & 63);
    const float* src = (col < 64) ? kr : ki;
    #pragma unroll
    for (int j = 0; j < 4; ++j) {
        const int sl = h * 4 + j;
        const int c  = sl & 3;
        union { unsigned short u[8]; uint4 v; } pk;
        #pragma unroll
        for (int i = 0; i < 8; ++i) {
            const int s = kt * 32 + c * 8 + i;
            const int t = (s == 0) ? 512 : s;
            const float v = src[t * NFILT + bin];
            const unsigned short hi = bf16rn(v);
            pk.u[i] = h ? bf16rn(v - __uint_as_float((unsigned int)hi << 16)) : hi;
        }
        *reinterpret_cast<uint4*>(&chunk[col * 64 + ((sl ^ (col & 7)) << 3)]) = pk.v;
    }
}

// ---------------------------------------------------------------------------
// Folded GEMM (r13 kernel, 330us @ MfmaUtil 27%) with the K-loop reordered
// to a counted raw-barrier schedule. r13 order STAGE;sync;COMPUTE;sync
// exposed the full stage latency at the first sync (vmcnt(0) drain right
// after issue). New per-kt order:
//   ds_read frags -> lgkmcnt(0)+sched_barrier (rule #18) -> s_barrier
//   (all waves done READING buf) -> STAGE(kt+1) into same buf (in flight)
//   -> 48 MFMAs (setprio) -> vmcnt(0) -> s_barrier (buf ready).
// Stage latency (~900cy) hides under the MFMA cluster; single 48 KB buffer
// keeps 2 blocks/CU. Epilogue re^2 tile aliases the buffer.
// ---------------------------------------------------------------------------
__global__ __launch_bounds__(256, 2) void spec_gemm2(
    const unsigned short* __restrict__ sH, const unsigned short* __restrict__ sL,
    const unsigned short* __restrict__ dH, const unsigned short* __restrict__ dL,
    const unsigned short* __restrict__ wsB,
    float* __restrict__ out, unsigned int* __restrict__ wmax,
    int sig0, int nsig)
{
    __shared__ unsigned short smem[24576];  // 48 KB: wn*{A 8192us | B 4096us}

    const int tid  = threadIdx.x;
    const int lane = tid & 63, w = tid >> 6;    // 4 waves
    const int wm = w & 1, wn = w >> 1;          // waves 0,1 -> wn=0 (cos); 2,3 -> wn=1 (sin)
    const int l15 = lane & 15, l16 = lane >> 4;

    const int phys = blockIdx.x;                // 0 .. nsig*64-1
    const int xcd  = phys & 7, slot = phys >> 3;
    const int nt   = slot & 7;
    const int mt   = xcd * nsig + (slot >> 3);  // within-pass mt
    const int sig  = sig0 + (mt >> 3);
    const int f0   = (mt & 7) * 128;            // within-signal frame base
    const unsigned short* bchunks = wsB + (size_t)nt * KT2 * CHUNK_US;

    const unsigned short* __restrict__ pH = wn ? dH : sH;
    const unsigned short* __restrict__ pL = wn ? dL : sL;

    // A gather lane constants: lane = (rl row-in-8, jj 16B-slot); LDS pos jj of
    // row r must hold global slot q = jj ^ (r&7); q<4 -> hi plane octet q,
    // q>=4 -> lo plane octet q-4.
    const int rl = lane >> 3, jj = lane & 7;
    const int q  = jj ^ rl;
    const unsigned short* apl = (q < 4) ? pH : pL;
    const unsigned short* agsrc[8];
    #pragma unroll
    for (int i = 0; i < 8; ++i)
        agsrc[i] = apl + (size_t)(mt * 128 + wm * 64 + i * 8 + rl) * 512 + (q & 3) * 8;

    unsigned short* Areg  = smem + wn * 12288;
    unsigned short* Breg  = Areg + 8192;
    unsigned short* aldst = Areg + wm * 4096;   // wave stages rows wm*64..+64
    unsigned short* bldst = Breg + wm * 2048;   // wave stages 4 KB of B

    f32x4 acc[4][4];
    #pragma unroll
    for (int i = 0; i < 4; ++i)
        #pragma unroll
        for (int j = 0; j < 4; ++j)
            #pragma unroll
            for (int r = 0; r < 4; ++r) acc[i][j][r] = 0.0f;

    #define STAGE(ktv)                                                         \
        {                                                                      \
            _Pragma("unroll")                                                  \
            for (int i = 0; i < 8; ++i)                                        \
                __builtin_amdgcn_global_load_lds(                              \
                    (const __attribute__((address_space(1))) unsigned int*)(agsrc[i] + (ktv) * 32), \
                    (__attribute__((address_space(3))) unsigned int*)(aldst + i * 512), \
                    16, 0, 0);                                                 \
            const unsigned short* gBs = bchunks + (size_t)(ktv) * CHUNK_US + wn * 4096 + wm * 2048; \
            _Pragma("unroll")                                                  \
            for (int i = 0; i < 4; ++i)                                        \
                __builtin_amdgcn_global_load_lds(                              \
                    (const __attribute__((address_space(1))) unsigned int*)(gBs + i * 512 + lane * 8), \
                    (__attribute__((address_space(3))) unsigned int*)(bldst + i * 512), \
                    16, 0, 0);                                                 \
        }

    // prologue: stage kt=0, wait, barrier -> buf valid
    STAGE(0)
    asm volatile("s_waitcnt vmcnt(0)" ::: "memory");
    __builtin_amdgcn_s_barrier();

    #pragma unroll 1
    for (int kt = 0; kt < KT2; ++kt) {
        // --- fragment loads from buf (registers) ---
        short8 ah[4], al[4], bh[4], bl[4];
        #pragma unroll
        for (int mf = 0; mf < 4; ++mf) {
            const int row = wm * 64 + mf * 16 + l15;
            const unsigned short* ab = Areg + row * 64;
            ah[mf] = *reinterpret_cast<const short8*>(ab + ((l16 ^ (row & 7)) << 3));
            al[mf] = *reinterpret_cast<const short8*>(ab + (((4 + l16) ^ (row & 7)) << 3));
        }
        #pragma unroll
        for (int nf = 0; nf < 4; ++nf) {
            const int coll = nf * 16 + l15;
            const unsigned short* bb = Breg + coll * 64;
            bh[nf] = *reinterpret_cast<const short8*>(bb + ((l16 ^ (coll & 7)) << 3));
            bl[nf] = *reinterpret_cast<const short8*>(bb + (((4 + l16) ^ (coll & 7)) << 3));
        }
        asm volatile("s_waitcnt lgkmcnt(0)" ::: "memory");
        __builtin_amdgcn_sched_barrier(0);
        __builtin_amdgcn_s_barrier();          // all waves done READING buf

        if (kt + 1 < KT2) STAGE(kt + 1)        // overwrite buf, in flight

        __builtin_amdgcn_s_setprio(1);
        #pragma unroll
        for (int nf = 0; nf < 4; ++nf)
            #pragma unroll
            for (int mf = 0; mf < 4; ++mf) {
                acc[mf][nf] = __builtin_amdgcn_mfma_f32_16x16x32_bf16(ah[mf], bh[nf], acc[mf][nf], 0, 0, 0);
                acc[mf][nf] = __builtin_amdgcn_mfma_f32_16x16x32_bf16(al[mf], bh[nf], acc[mf][nf], 0, 0, 0);
                acc[mf][nf] = __builtin_amdgcn_mfma_f32_16x16x32_bf16(ah[mf], bl[nf], acc[mf][nf], 0, 0, 0);
            }
        __builtin_amdgcn_s_setprio(0);

        asm volatile("s_waitcnt vmcnt(0)" ::: "memory");
        __builtin_amdgcn_s_barrier();          // buf ready for kt+1
    }
    #undef STAGE

    // ---- epilogue: wn=0 writes re^2 (bf16) into smem (aliases buffers);
    //      wn=1 combines re^2+im^2, dB, store + per-batch max ----
    if (wn == 0) {
        #pragma unroll
        for (int mf = 0; mf < 4; ++mf)
            #pragma unroll
            for (int nf = 0; nf < 4; ++nf) {
                const int binl = nf * 16 + l15;
                #pragma unroll
                for (int r = 0; r < 4; ++r) {
                    const int row = wm * 64 + mf * 16 + l16 * 4 + r;
                    const float v = acc[mf][nf][r];
                    smem[row * 68 + binl] = bf16rn(v * v);
                }
            }
    }
    __syncthreads();
    if (wn == 1) {
        const int batch = sig >> 1, ch = sig & 1;
        float lmax = -3.0e38f;
        #pragma unroll
        for (int mf = 0; mf < 4; ++mf)
            #pragma unroll
            for (int nf = 0; nf < 4; ++nf) {
                const int binl = nf * 16 + l15;
                const int bin  = nt * 64 + binl;
                #pragma unroll
                for (int r = 0; r < 4; ++r) {
                    const int row = wm * 64 + mf * 16 + l16 * 4 + r;
                    const float v = acc[mf][nf][r];
                    const float re2 = __uint_as_float((unsigned int)smem[row * 68 + binl] << 16);
                    const float p = re2 + v * v;
                    const float d = 10.0f * log10f(fmaxf(p, 1e-10f));
                    const int frame = f0 + row;
                    out[((long)(batch * NFILT + bin) * NFRAME + frame) * 2 + ch] = d;
                    lmax = fmaxf(lmax, d);
                }
            }
        #pragma unroll
        for (int off = 32; off > 0; off >>= 1) lmax = fmaxf(lmax, __shfl_xor(lmax, off));
        if (lane == 0) atomicMax(&wmax[batch], f2key(lmax));
    }
}

// ---------------------------------------------------------------------------
// Mid-tier GEMM (round-3 proven kernel, K=1024, LDS-staged A) for small ws.
// ---------------------------------------------------------------------------
__global__ __launch_bounds__(256) void build_B(const float* __restrict__ kr,
                                               const float* __restrict__ ki,
                                               unsigned short* __restrict__ wsB)
{
    const int nt = blockIdx.x >> 5;
    const int kt = blockIdx.x & 31;
    unsigned short* chunk = wsB + (size_t)blockIdx.x * CHUNK_US;
    const int col = threadIdx.x >> 1;
    const int h   = threadIdx.x & 1;
    const int bin = nt * 64 + (col >> 1);
    const float* src = (col & 1) ? ki : kr;
    #pragma unroll
    for (int j = 0; j < 4; ++j) {
        const int sl = h * 4 + j;
        const int c  = sl & 3;
        union { unsigned short u[8]; uint4 v; } pk;
        #pragma unroll
        for (int i = 0; i < 8; ++i) {
            const int t = kt * 32 + c * 8 + i;
            const float v = src[t * NFILT + bin];
            const unsigned short hi = bf16rn(v);
            pk.u[i] = h ? bf16rn(v - __uint_as_float((unsigned int)hi << 16)) : hi;
        }
        *reinterpret_cast<uint4*>(&chunk[col * 64 + ((sl ^ (col & 7)) << 3)]) = pk.v;
    }
}

__global__ __launch_bounds__(256, 2) void spec_gemm_mid(
    const float* __restrict__ x, const unsigned short* __restrict__ wsB,
    float* __restrict__ out, unsigned int* __restrict__ wmax)
{
    __shared__ unsigned short Ad[2][128][64];
    __shared__ unsigned short Bd[2][128][64];

    const int tid  = threadIdx.x;
    const int lane = tid & 63, w = tid >> 6;
    const int wm = w >> 1, wn = w & 1;
    const int l15 = lane & 15, l16 = lane >> 4;
    const int mt = blockIdx.x, nt = blockIdx.y;
    const int sig = mt >> 3, f0 = (mt & 7) * 128;
    const long sb = (long)sig * LSRC;

    const int arow = tid >> 1, ac2 = tid & 1;
    const int abase_p = (f0 + arow) * NHOP - PAD_L + ac2 * 16;
    const unsigned short* bchunks = wsB + (size_t)nt * KT1 * CHUNK_US;

    f32x4 acc[4][4];
    #pragma unroll
    for (int i = 0; i < 4; ++i)
        #pragma unroll
        for (int j = 0; j < 4; ++j)
            #pragma unroll
            for (int r = 0; r < 4; ++r) acc[i][j][r] = 0.0f;

    float va[16];

    #define LOAD_A(ktv)                                                        \
        {                                                                      \
            const int p0 = abase_p + (ktv) * 32;                               \
            if (p0 >= 0 && p0 + 16 <= LSRC) {                                  \
                *reinterpret_cast<float4*>(&va[0])  = *reinterpret_cast<const float4*>(x + sb + p0);      \
                *reinterpret_cast<float4*>(&va[4])  = *reinterpret_cast<const float4*>(x + sb + p0 + 4);  \
                *reinterpret_cast<float4*>(&va[8])  = *reinterpret_cast<const float4*>(x + sb + p0 + 8);  \
                *reinterpret_cast<float4*>(&va[12]) = *reinterpret_cast<const float4*>(x + sb + p0 + 12); \
            } else {                                                           \
                _Pragma("unroll")                                              \
                for (int i = 0; i < 16; ++i) {                                 \
                    const int p = p0 + i;                                      \
                    va[i] = (p >= 0 && p < LSRC) ? x[sb + p] : 0.0f;           \
                }                                                              \
            }                                                                  \
        }

    #define LOAD_B(ktv, nb)                                                    \
        {                                                                      \
            const char* g = (const char*)(bchunks + (size_t)(ktv) * CHUNK_US); \
            char* l = (char*)&Bd[nb][0][0];                                    \
            _Pragma("unroll")                                                  \
            for (int i = 0; i < 4; ++i) {                                      \
                const int off = i * 4096 + w * 1024;                           \
                __builtin_amdgcn_global_load_lds(                              \
                    (const __attribute__((address_space(1))) unsigned int*)(g + off + lane * 16), \
                    (__attribute__((address_space(3))) unsigned int*)(l + off), \
                    16, 0, 0);                                                 \
            }                                                                  \
        }

    #define WRITE_A(nb)                                                       \
        {                                                                      \
            unsigned short* ab = &Ad[nb][arow][0];                             \
            _Pragma("unroll")                                                  \
            for (int j = 0; j < 2; ++j) {                                      \
                union { unsigned short u[8]; uint4 v; } hv, lv;                \
                _Pragma("unroll")                                              \
                for (int i = 0; i < 8; ++i) {                                  \
                    const float vv = va[j * 8 + i];                            \
                    const unsigned short hi = bf16rn(vv);                      \
                    hv.u[i] = hi;                                              \
                    lv.u[i] = bf16rn(vv - __uint_as_float((unsigned int)hi << 16)); \
                }                                                              \
                const int c = ac2 * 2 + j;                                     \
                *reinterpret_cast<uint4*>(ab + (((c) ^ (arow & 7)) << 3))     = hv.v; \
                *reinterpret_cast<uint4*>(ab + (((4 + c) ^ (arow & 7)) << 3)) = lv.v; \
            }                                                                  \
        }

    LOAD_A(0)
    LOAD_B(0, 0)
    WRITE_A(0)
    __syncthreads();

    #pragma unroll 1
    for (int kt = 0; kt < KT1; ++kt) {
        const int cur = kt & 1, nxt = cur ^ 1;
        const bool pf = (kt + 1 < KT1);
        if (pf) {
            LOAD_A(kt + 1)
            LOAD_B(kt + 1, nxt)
        }
        short8 ah[4], al[4];
        #pragma unroll
        for (int mf = 0; mf < 4; ++mf) {
            const int row = wm * 64 + mf * 16 + l15;
            const unsigned short* ab = &Ad[cur][row][0];
            ah[mf] = *reinterpret_cast<const short8*>(ab + ((l16 ^ (row & 7)) << 3));
            al[mf] = *reinterpret_cast<const short8*>(ab + (((4 + l16) ^ (row & 7)) << 3));
        }
        __builtin_amdgcn_s_setprio(1);
        #pragma unroll
        for (int nf = 0; nf < 4; ++nf) {
            const int col = wn * 64 + nf * 16 + l15;
            const unsigned short* bb = &Bd[cur][col][0];
            const short8 bh = *reinterpret_cast<const short8*>(bb + ((l16 ^ (col & 7)) << 3));
            const short8 bl = *reinterpret_cast<const short8*>(bb + (((4 + l16) ^ (col & 7)) << 3));
            #pragma unroll
            for (int mf = 0; mf < 4; ++mf) {
                acc[mf][nf] = __builtin_amdgcn_mfma_f32_16x16x32_bf16(ah[mf], bh, acc[mf][nf], 0, 0, 0);
                acc[mf][nf] = __builtin_amdgcn_mfma_f32_16x16x32_bf16(al[mf], bh, acc[mf][nf], 0, 0, 0);
                acc[mf][nf] = __builtin_amdgcn_mfma_f32_16x16x32_bf16(ah[mf], bl, acc[mf][nf], 0, 0, 0);
            }
        }
        __builtin_amdgcn_s_setprio(0);
        if (pf) WRITE_A(nxt)
        __syncthreads();
    }
    #undef LOAD_A
    #undef LOAD_B
    #undef WRITE_A

    const int batch = sig >> 1, ch = sig & 1;
    float lmax = -3.0e38f;
    #pragma unroll
    for (int mf = 0; mf < 4; ++mf)
        #pragma unroll
        for (int nf = 0; nf < 4; ++nf) {
            const int col = nt * 128 + wn * 64 + nf * 16 + l15;
            const int bin = col >> 1;
            #pragma unroll
            for (int r = 0; r < 4; ++r) {
                const float v  = acc[mf][nf][r];
                const float sq = v * v;
                const float p  = sq + __shfl_xor(sq, 1);
                if (!(lane & 1)) {
                    const int frame = f0 + wm * 64 + mf * 16 + l16 * 4 + r;
                    const float d = 10.0f * log10f(fmaxf(p, 1e-10f));
                    out[((long)(batch * NFILT + bin) * NFRAME + frame) * 2 + ch] = d;
                    lmax = fmaxf(lmax, d);
                }
            }
        }
    #pragma unroll
    for (int off = 32; off > 0; off >>= 1) lmax = fmaxf(lmax, __shfl_xor(lmax, off));
    if (lane == 0) atomicMax(&wmax[batch], f2key(lmax));
}

// ---------------------------------------------------------------------------
// Nyquist bin (512): block = 1 signal x 64 frames, x + coeffs staged in LDS.
// ---------------------------------------------------------------------------
__global__ __launch_bounds__(256, 2) void spec_nyq(
    const float* __restrict__ x, const float* __restrict__ kr,
    const float* __restrict__ ki, float* __restrict__ out,
    unsigned int* __restrict__ wmax)
{
    __shared__ float xs[17152];
    __shared__ float kc[1024], ks[1024];
    const int sig = blockIdx.x >> 4, ft = blockIdx.x & 15;
    const int f0 = ft * 64;
    const long sb = (long)sig * LSRC;
    const int start = f0 * NHOP - PAD_L;
    for (int i = threadIdx.x; i < 17152; i += 256) {
        const int p = start + i;
        xs[i] = (p >= 0 && p < LSRC) ? x[sb + p] : 0.0f;
    }
    for (int t = threadIdx.x; t < 1024; t += 256) {
        kc[t] = kr[t * NFILT + 512];
        ks[t] = ki[t * NFILT + 512];
    }
    __syncthreads();
    const int fr = threadIdx.x >> 2, q = threadIdx.x & 3;
    const int rot = ((fr + q) & 7) * 4;
    float re = 0.0f, im = 0.0f;
    #pragma unroll 4
    for (int j = 0; j < 256; j += 4) {
        const int je = (j + rot) & 255;
        const float4 a = *reinterpret_cast<const float4*>(&xs[fr * 256 + q * 256 + je]);
        const float4 c = *reinterpret_cast<const float4*>(&kc[q * 256 + je]);
        const float4 s = *reinterpret_cast<const float4*>(&ks[q * 256 + je]);
        re = fmaf(a.x, c.x, re); re = fmaf(a.y, c.y, re);
        re = fmaf(a.z, c.z, re); re = fmaf(a.w, c.w, re);
        im = fmaf(a.x, s.x, im); im = fmaf(a.y, s.y, im);
        im = fmaf(a.z, s.z, im); im = fmaf(a.w, s.w, im);
    }
    re += __shfl_xor(re, 1); re += __shfl_xor(re, 2);
    im += __shfl_xor(im, 1); im += __shfl_xor(im, 2);
    const int batch = sig >> 1, ch = sig & 1;
    float lmax = -3.0e38f;
    if (q == 0) {
        const float p = re * re + im * im;
        const float d = 10.0f * log10f(fmaxf(p, 1e-10f));
        out[((long)(batch * NFILT + 512) * NFRAME + (f0 + fr)) * 2 + ch] = d;
        lmax = d;
    }
    #pragma unroll
    for (int off = 32; off > 0; off >>= 1) lmax = fmaxf(lmax, __shfl_xor(lmax, off));
    if ((threadIdx.x & 63) == 0) atomicMax(&wmax[batch], f2key(lmax));
}

__global__ __launch_bounds__(256) void finalize(
    float* __restrict__ out, const unsigned int* __restrict__ wmax, long n4)
{
    const long stride = (long)gridDim.x * 256;
    for (long i4 = blockIdx.x * 256L + threadIdx.x; i4 < n4; i4 += stride) {
        const long i = i4 * 4;
        const int b  = (int)(i / PER_B);
        const float m = key2f(wmax[b]);
        float4 v = reinterpret_cast<float4*>(out)[i4];
        v.x = fmaxf(v.x - m, -80.0f);
        v.y = fmaxf(v.y - m, -80.0f);
        v.z = fmaxf(v.z - m, -80.0f);
        v.w = fmaxf(v.w - m, -80.0f);
        reinterpret_cast<float4*>(out)[i4] = v;
    }
}

// ---------------------------------------------------------------------------
// Fallback (fp32 vector path) if ws tiny.
// ---------------------------------------------------------------------------
namespace fb {
constexpr int TILE_F = 32;
constexpr int SPAN   = (TILE_F - 1) * NHOP + NDFT;
}

__global__ __launch_bounds__(256) void spec_main_fb(
    const float* __restrict__ x, const float* __restrict__ kr,
    const float* __restrict__ ki, float* __restrict__ out,
    unsigned int* __restrict__ wmax)
{
    __shared__ float xs[fb::SPAN];
    const int s   = blockIdx.x;
    const int f0  = blockIdx.y * fb::TILE_F;
    const int tid = threadIdx.x;
    const long sig_base = (long)s * LSRC;
    const int start = f0 * NHOP - PAD_L;
    for (int i = tid; i < fb::SPAN; i += 256) {
        const int p = start + i;
        xs[i] = (p >= 0 && p < LSRC) ? x[sig_base + p] : 0.0f;
    }
    __syncthreads();
    const int b0 = tid, b1 = tid + 256;
    float ar0[fb::TILE_F], ai0[fb::TILE_F], ar1[fb::TILE_F], ai1[fb::TILE_F];
    #pragma unroll
    for (int f = 0; f < fb::TILE_F; ++f) { ar0[f]=0.f; ai0[f]=0.f; ar1[f]=0.f; ai1[f]=0.f; }
    #pragma unroll 1
    for (int t = 0; t < NDFT; t += 4) {
        float br0[4], bq0[4], br1[4], bq1[4];
        #pragma unroll
        for (int j = 0; j < 4; ++j) {
            br0[j] = kr[(t + j) * NFILT + b0]; bq0[j] = ki[(t + j) * NFILT + b0];
            br1[j] = kr[(t + j) * NFILT + b1]; bq1[j] = ki[(t + j) * NFILT + b1];
        }
        #pragma unroll
        for (int f = 0; f < fb::TILE_F; ++f) {
            const float4 a = *reinterpret_cast<const float4*>(&xs[t + NHOP * f]);
            ar0[f]=fmaf(a.x,br0[0],ar0[f]); ar0[f]=fmaf(a.y,br0[1],ar0[f]);
            ar0[f]=fmaf(a.z,br0[2],ar0[f]); ar0[f]=fmaf(a.w,br0[3],ar0[f]);
            ai0[f]=fmaf(a.x,bq0[0],ai0[f]); ai0[f]=fmaf(a.y,bq0[1],ai0[f]);
            ai0[f]=fmaf(a.z,bq0[2],ai0[f]); ai0[f]=fmaf(a.w,bq0[3],ai0[f]);
            ar1[f]=fmaf(a.x,br1[0],ar1[f]); ar1[f]=fmaf(a.y,br1[1],ar1[f]);
            ar1[f]=fmaf(a.z,br1[2],ar1[f]); ar1[f]=fmaf(a.w,br1[3],ar1[f]);
            ai1[f]=fmaf(a.x,bq1[0],ai1[f]); ai1[f]=fmaf(a.y,bq1[1],ai1[f]);
            ai1[f]=fmaf(a.z,bq1[2],ai1[f]); ai1[f]=fmaf(a.w,bq1[3],ai1[f]);
        }
    }
    const int b = s >> 1, ch = s & 1;
    float lmax = -3.0e38f;
    #pragma unroll
    for (int f = 0; f < fb::TILE_F; ++f) {
        const int frame = f0 + f;
        const float p0 = ar0[f]*ar0[f] + ai0[f]*ai0[f];
        const float p1 = ar1[f]*ar1[f] + ai1[f]*ai1[f];
        const float d0 = 10.0f * log10f(fmaxf(p0, 1e-10f));
        const float d1 = 10.0f * log10f(fmaxf(p1, 1e-10f));
        lmax = fmaxf(lmax, fmaxf(d0, d1));
        out[((long)(b * NFILT + b0) * NFRAME + frame) * 2 + ch] = d0;
        out[((long)(b * NFILT + b1) * NFRAME + frame) * 2 + ch] = d1;
    }
    #pragma unroll
    for (int off = 32; off > 0; off >>= 1) lmax = fmaxf(lmax, __shfl_xor(lmax, off));
    if ((tid & 63) == 0) atomicMax(&wmax[b], f2key(lmax));
}

__global__ __launch_bounds__(256) void spec_nyq_fb(
    const float* __restrict__ x, const float* __restrict__ kr,
    const float* __restrict__ ki, float* __restrict__ out,
    unsigned int* __restrict__ wmax)
{
    const int gid   = blockIdx.x * 256 + threadIdx.x;
    const int s     = gid >> 10;
    const int frame = gid & 1023;
    const float* xp = x + (long)s * LSRC;
    const int start = frame * NHOP - PAD_L;
    float re = 0.f, im = 0.f;
    for (int t = 0; t < NDFT; ++t) {
        const int idx = start + t;
        const float a = (idx >= 0 && idx < LSRC) ? xp[idx] : 0.0f;
        re = fmaf(a, kr[t * NFILT + 512], re);
        im = fmaf(a, ki[t * NFILT + 512], im);
    }
    const float p = re * re + im * im;
    const float d = 10.0f * log10f(fmaxf(p, 1e-10f));
    const int b = s >> 1, ch = s & 1;
    out[((long)(b * NFILT + 512) * NFRAME + frame) * 2 + ch] = d;
    float lmax = d;
    #pragma unroll
    for (int off = 32; off > 0; off >>= 1) lmax = fmaxf(lmax, __shfl_xor(lmax, off));
    if ((threadIdx.x & 63) == 0) atomicMax(&wmax[b], f2key(lmax));
}

extern "C" void kernel_launch(void* const* d_in, const int* in_sizes, int n_in,
                              void* d_out, int out_size, void* d_ws, size_t ws_size,
                              hipStream_t stream) {
    const float* x  = (const float*)d_in[0];
    const float* kr = (const float*)d_in[1];
    const float* ki = (const float*)d_in[2];
    float* out = (float*)d_out;
    const long n4 = (long)out_size / 4;

    // folded tier: [wmax 128B][B2 2MB][sumH|sumL|diffH|diffL, nsig MB each]
    int nsig = 0;
    const int cands[4] = {64, 32, 16, 8};
    for (int c = 0; c < 4; ++c) {
        const size_t need = 128 + WSB2_BYTES + (size_t)cands[c] * 4 * 1048576;
        if (ws_size >= need) { nsig = cands[c]; break; }
    }

    if (nsig) {
        unsigned int* wmax   = (unsigned int*)d_ws;
        unsigned short* wsB2 = (unsigned short*)((char*)d_ws + 128);
        unsigned short* sH   = (unsigned short*)((char*)d_ws + 128 + WSB2_BYTES);
        const size_t pe = (size_t)nsig * PLANE_ELEMS_PER_SIG;
        unsigned short* sL = sH + pe;
        unsigned short* dH = sL + pe;
        unsigned short* dL = dH + pe;
        zero_ws<<<1, 64, 0, stream>>>(wmax);
        build_B2<<<128, 256, 0, stream>>>(kr, ki, wsB2);
        const int npass = 64 / nsig;
        for (int p = 0; p < npass; ++p) {
            fold_split<<<nsig * 256, 256, 0, stream>>>(x, sH, sL, dH, dL, p * nsig);
            spec_gemm2<<<nsig * 64, 256, 0, stream>>>(sH, sL, dH, dL, wsB2, out, wmax,
                                                      p * nsig, nsig);
        }
        spec_nyq<<<1024, 256, 0, stream>>>(x, kr, ki, out, wmax);
        finalize<<<2048, 256, 0, stream>>>(out, wmax, n4);
    } else if (ws_size >= WS_B_BYTES + 128) {
        unsigned short* wsB = (unsigned short*)d_ws;
        unsigned int* wmax  = (unsigned int*)((char*)d_ws + WS_B_BYTES);
        zero_ws<<<1, 64, 0, stream>>>(wmax);
        build_B<<<8 * KT1, 256, 0, stream>>>(kr, ki, wsB);
        spec_gemm_mid<<<dim3(512, 8), 256, 0, stream>>>(x, wsB, out, wmax);
        spec_nyq<<<1024, 256, 0, stream>>>(x, kr, ki, out, wmax);
        finalize<<<2048, 256, 0, stream>>>(out, wmax, n4);
    } else {
        unsigned int* wmax = (unsigned int*)d_ws;
        zero_ws<<<1, 64, 0, stream>>>(wmax);
        dim3 grid(64, NFRAME / fb::TILE_F);
        spec_main_fb<<<grid, 256, 0, stream>>>(x, kr, ki, out, wmax);
        spec_nyq_fb<<<(64 * NFRAME) / 256, 256, 0, stream>>>(x, kr, ki, out, wmax);
        finalize<<<2048, 256, 0, stream>>>(out, wmax, n4);
    }
}